// Round 2
// baseline (1138.592 us; speedup 1.0000x reference)
//
#include <hip/hip_runtime.h>

// ---- problem dims ----
#define SQ   2048
#define DM   768
#define NHD  12
#define DHD  64
#define FF   1536
#define NE   8
#define NL   2
#define NV   32000

typedef __attribute__((ext_vector_type(8))) short bf16x8;
typedef __attribute__((ext_vector_type(4))) float f32x4;

__device__ __forceinline__ unsigned short f2bf(float f) {
  unsigned u = __float_as_uint(f);
  return (unsigned short)((u + 0x7fffu + ((u >> 16) & 1u)) >> 16);
}
__device__ __forceinline__ float bf2f(unsigned short h) {
  return __uint_as_float(((unsigned)h) << 16);
}

// ---------------- embedding: x = emb[tok]*sqrt(D) ----------------
__global__ __launch_bounds__(256) void embed_k(const int* __restrict__ tok,
    const float* __restrict__ emb, float* __restrict__ x,
    unsigned short* __restrict__ xbf) {
  int idx = blockIdx.x * 256 + threadIdx.x;   // < 2048*768
  int s = idx / DM, d = idx % DM;
  float v = emb[(size_t)tok[s] * DM + d] * 27.712812921102035f;
  x[idx] = v;
  xbf[idx] = f2bf(v);
}

// ---------------- generic bf16-MFMA GEMM ----------------
// 1-D grid, XCD-chunk swizzled, m-fastest decode (B-panel reuse within XCD L2).
// C[z][m][n] = scale * sum_k A[z][row(m)][k] * B[z][n][k] (+ bias[n])
template<bool BF16B, bool GATHER, bool BIAS, bool OBF16>
__global__ __launch_bounds__(256) void gemm_k(
    const unsigned short* __restrict__ A, long long lda, long long a_z,
    const void* __restrict__ Bp, long long ldb, long long b_z,
    const float* __restrict__ bias,
    void* __restrict__ C, long long ldc, long long c_z,
    int M, int N, int Kd, float scale,
    const int* __restrict__ glist, long long gl_z,
    const int* __restrict__ cnt, int mT, int nT)
{
  // bijective XCD-chunked swizzle (m204): physical bid -> logical work id
  int nwg = gridDim.x;
  int bid = blockIdx.x;
  int q = nwg >> 3, r = nwg & 7;
  int xcd = bid & 7, j = bid >> 3;
  int wid = (xcd < r ? xcd * (q + 1) : r * (q + 1) + (xcd - r) * q) + j;

  int per_z = mT * nT;
  int z = wid / per_z;
  int rem = wid - z * per_z;
  int nt = rem / mT;
  int mt = rem - nt * mT;

  int Mz = cnt ? cnt[z] : M;
  int m0 = mt * 128;
  int n0 = nt * 128;
  if (m0 >= Mz) return;
  const unsigned short* Ab = A + (size_t)z * a_z;
  const int* gl = nullptr;
  if constexpr (GATHER) gl = glist + (size_t)z * gl_z;

  __shared__ unsigned short As[128][72];  // 64 + 8 pad
  __shared__ unsigned short Bs[128][72];

  int t = threadIdx.x;
  int w = t >> 6, lane = t & 63;
  int wm = (w >> 1) * 64, wn = (w & 1) * 64;
  int fr = lane & 15, ks = (lane >> 4) * 8;

  f32x4 acc[4][4] = {};

  for (int k0 = 0; k0 < Kd; k0 += 64) {
    #pragma unroll
    for (int i = 0; i < 4; ++i) {
      int c = t + i * 256;
      int rr = c >> 3, sl = c & 7;
      int gr = m0 + rr; if (gr >= Mz) gr = Mz - 1;
      int arow; if constexpr (GATHER) arow = gl[gr]; else arow = gr;
      *(int4*)&As[rr][sl * 8] =
          *(const int4*)(Ab + (size_t)arow * lda + k0 + sl * 8);
    }
    if constexpr (BF16B) {
      const unsigned short* Bb = (const unsigned short*)Bp + (size_t)z * b_z;
      #pragma unroll
      for (int i = 0; i < 4; ++i) {
        int c = t + i * 256;
        int rr = c >> 3, sl = c & 7;
        int br = n0 + rr; if (br >= N) br = N - 1;
        *(int4*)&Bs[rr][sl * 8] =
            *(const int4*)(Bb + (size_t)br * ldb + k0 + sl * 8);
      }
    } else {
      const float* Bb = (const float*)Bp + (size_t)z * b_z;
      #pragma unroll
      for (int i = 0; i < 4; ++i) {
        int c = t + i * 256;
        int rr = c >> 3, sl = c & 7;
        int br = n0 + rr; if (br >= N) br = N - 1;
        const float* qp = Bb + (size_t)br * ldb + k0 + sl * 8;
        float4 f0 = *(const float4*)qp;
        float4 f1 = *(const float4*)(qp + 4);
        int4 pk = make_int4(
            (int)((unsigned)f2bf(f0.x) | ((unsigned)f2bf(f0.y) << 16)),
            (int)((unsigned)f2bf(f0.z) | ((unsigned)f2bf(f0.w) << 16)),
            (int)((unsigned)f2bf(f1.x) | ((unsigned)f2bf(f1.y) << 16)),
            (int)((unsigned)f2bf(f1.z) | ((unsigned)f2bf(f1.w) << 16)));
        *(int4*)&Bs[rr][sl * 8] = pk;
      }
    }
    __syncthreads();
    #pragma unroll
    for (int kb = 0; kb < 2; ++kb) {
      bf16x8 af[4], bv[4];
      #pragma unroll
      for (int m = 0; m < 4; ++m)
        af[m] = *(const bf16x8*)&As[wm + m * 16 + fr][kb * 32 + ks];
      #pragma unroll
      for (int n = 0; n < 4; ++n)
        bv[n] = *(const bf16x8*)&Bs[wn + n * 16 + fr][kb * 32 + ks];
      #pragma unroll
      for (int m = 0; m < 4; ++m)
        #pragma unroll
        for (int n = 0; n < 4; ++n)
          acc[m][n] = __builtin_amdgcn_mfma_f32_16x16x32_bf16(
              af[m], bv[n], acc[m][n], 0, 0, 0);
    }
    __syncthreads();
  }

  // epilogue: C/D layout col=lane&15, row=(lane>>4)*4+reg
  int rb = (lane >> 4) * 4;
  #pragma unroll
  for (int m = 0; m < 4; ++m) {
    #pragma unroll
    for (int n = 0; n < 4; ++n) {
      int col = n0 + wn + n * 16 + fr;
      if (col >= N) continue;
      #pragma unroll
      for (int rr = 0; rr < 4; ++rr) {
        int row = m0 + wm + m * 16 + rb + rr;
        if (row >= Mz) continue;
        float v = acc[m][n][rr] * scale;
        if constexpr (BIAS) v += bias[col];
        size_t off = (size_t)z * c_z + (size_t)row * ldc + col;
        if constexpr (OBF16) ((unsigned short*)C)[off] = f2bf(v);
        else                 ((float*)C)[off] = v;
      }
    }
  }
}

// ---------------- V transpose: vt[h][d][k] = qkv[k][2D + h*64 + d] ----------------
__global__ __launch_bounds__(256) void transpose_v_k(
    const unsigned short* __restrict__ qkv, unsigned short* __restrict__ vt) {
  int kt = blockIdx.x;   // 0..31
  int h  = blockIdx.y;   // 0..11
  __shared__ unsigned short tile[64][72];
  int t = threadIdx.x;
  int r = t >> 2;             // 0..63
  int c0 = (t & 3) * 16;      // 0,16,32,48
  const unsigned short* src =
      qkv + (size_t)(kt * 64 + r) * (3 * DM) + 2 * DM + h * DHD + c0;
  *(int4*)&tile[r][c0]     = *(const int4*)(src);
  *(int4*)&tile[r][c0 + 8] = *(const int4*)(src + 8);
  __syncthreads();
  unsigned u[8];
  #pragma unroll
  for (int j = 0; j < 8; ++j)
    u[j] = (unsigned)tile[c0 + 2 * j][r] | ((unsigned)tile[c0 + 2 * j + 1][r] << 16);
  unsigned short* dst = vt + (size_t)(h * DHD + r) * SQ + kt * 64 + c0;
  *(int4*)dst       = make_int4((int)u[0], (int)u[1], (int)u[2], (int)u[3]);
  *(int4*)(dst + 8) = make_int4((int)u[4], (int)u[5], (int)u[6], (int)u[7]);
}

// ---------------- softmax over one score row (2048, bf16, in-place) ----------------
__global__ __launch_bounds__(256) void softmax_k(unsigned short* __restrict__ sc) {
  unsigned short* p = sc + (size_t)blockIdx.x * SQ;
  int t = threadIdx.x;
  int4 raw = ((int4*)p)[t];
  unsigned short* h = (unsigned short*)&raw;
  float f[8];
  float mx = -1e30f;
  #pragma unroll
  for (int j = 0; j < 8; ++j) { f[j] = bf2f(h[j]); mx = fmaxf(mx, f[j]); }
  #pragma unroll
  for (int o = 32; o; o >>= 1) mx = fmaxf(mx, __shfl_xor(mx, o));
  __shared__ float rm[4], rs[4];
  int w = t >> 6;
  if ((t & 63) == 0) rm[w] = mx;
  __syncthreads();
  mx = fmaxf(fmaxf(rm[0], rm[1]), fmaxf(rm[2], rm[3]));
  float s = 0.f;
  #pragma unroll
  for (int j = 0; j < 8; ++j) { f[j] = expf(f[j] - mx); s += f[j]; }
  #pragma unroll
  for (int o = 32; o; o >>= 1) s += __shfl_xor(s, o);
  if ((t & 63) == 0) rs[w] = s;
  __syncthreads();
  s = rs[0] + rs[1] + rs[2] + rs[3];
  float inv = 1.f / s;
  #pragma unroll
  for (int j = 0; j < 8; ++j) h[j] = f2bf(f[j] * inv);
  ((int4*)p)[t] = raw;
}

// ---------------- x = LN(x + add) ----------------
__global__ __launch_bounds__(256) void add_ln_k(const float* __restrict__ xin,
    const float* __restrict__ add, const float* __restrict__ w,
    const float* __restrict__ b, float* __restrict__ xout,
    unsigned short* __restrict__ xbf) {
  int row = blockIdx.x, t = threadIdx.x;
  const float* xi = xin + (size_t)row * DM;
  const float* ai = add + (size_t)row * DM;
  float v[3]; float s = 0.f, sq = 0.f;
  #pragma unroll
  for (int i = 0; i < 3; ++i) {
    int idx = t + i * 256;
    v[i] = xi[idx] + ai[idx];
    s += v[i]; sq += v[i] * v[i];
  }
  #pragma unroll
  for (int o = 32; o; o >>= 1) { s += __shfl_xor(s, o); sq += __shfl_xor(sq, o); }
  __shared__ float rsm[4], rqm[4];
  int wv = t >> 6;
  if ((t & 63) == 0) { rsm[wv] = s; rqm[wv] = sq; }
  __syncthreads();
  s = rsm[0] + rsm[1] + rsm[2] + rsm[3];
  sq = rqm[0] + rqm[1] + rqm[2] + rqm[3];
  float mean = s * (1.f / 768.f);
  float var = sq * (1.f / 768.f) - mean * mean;
  float inv = rsqrtf(var + 1e-5f);
  float* xo = xout + (size_t)row * DM;
  unsigned short* xb = xbf + (size_t)row * DM;
  #pragma unroll
  for (int i = 0; i < 3; ++i) {
    int idx = t + i * 256;
    float y = (v[i] - mean) * inv * w[idx] + b[idx];
    xo[idx] = y; xb[idx] = f2bf(y);
  }
}

// ---------------- gate: 8 dots, top-2, softmax, expert bucket lists ----------------
__global__ void gate_topk_k(const float* __restrict__ x, const float* __restrict__ gw,
    float* __restrict__ tw, int* __restrict__ ti, int* __restrict__ cnt,
    int* __restrict__ lists, int* __restrict__ slot) {
  int sIdx = blockIdx.x, lane = threadIdx.x;  // 64 threads
  const float* xr = x + (size_t)sIdx * DM;
  float acc[NE] = {};
  for (int d = lane; d < DM; d += 64) {
    float xv = xr[d];
    #pragma unroll
    for (int e = 0; e < NE; ++e) acc[e] += xv * gw[e * DM + d];
  }
  #pragma unroll
  for (int e = 0; e < NE; ++e) {
    #pragma unroll
    for (int o = 32; o; o >>= 1) acc[e] += __shfl_down(acc[e], o);
  }
  if (lane == 0) {
    float v0 = -1e30f, v1 = -1e30f; int i0 = 0, i1 = 0;
    #pragma unroll
    for (int e = 0; e < NE; ++e) {
      float v = acc[e];
      if (v > v0) { v1 = v0; i1 = i0; v0 = v; i0 = e; }
      else if (v > v1) { v1 = v; i1 = e; }
    }
    float e1 = expf(v1 - v0);
    float inv = 1.f / (1.f + e1);
    tw[sIdx * 2] = inv; tw[sIdx * 2 + 1] = e1 * inv;
    ti[sIdx * 2] = i0;  ti[sIdx * 2 + 1] = i1;
    int p0 = atomicAdd(&cnt[i0], 1); lists[i0 * SQ + p0] = sIdx; slot[sIdx * 2] = p0;
    int p1 = atomicAdd(&cnt[i1], 1); lists[i1 * SQ + p1] = sIdx; slot[sIdx * 2 + 1] = p1;
  }
}

__global__ void zero_k(int* __restrict__ c) {
  if (threadIdx.x < NE) c[threadIdx.x] = 0;
}

// ---------------- hh = silu(hg) * hu (in-place into hg) ----------------
__global__ __launch_bounds__(256) void silu_mul_k(unsigned short* __restrict__ hg,
    const unsigned short* __restrict__ hu, const int* __restrict__ cnt) {
  int e = blockIdx.y, sl = blockIdx.x;
  if (sl >= cnt[e]) return;
  size_t base = ((size_t)e * SQ + sl) * FF;
  int t = threadIdx.x;
  #pragma unroll
  for (int i = 0; i < FF / 256; ++i) {
    size_t idx = base + t + i * 256;
    float g = bf2f(hg[idx]);
    float u = bf2f(hu[idx]);
    float sv = g / (1.f + expf(-g));
    hg[idx] = f2bf(sv * u);
  }
}

// ---------------- moe combine + LN ----------------
__global__ __launch_bounds__(256) void combine_ln_k(const float* __restrict__ xin,
    const float* __restrict__ ye, const float* __restrict__ tw,
    const int* __restrict__ ti, const int* __restrict__ slot,
    const float* __restrict__ w, const float* __restrict__ b,
    float* __restrict__ xout, unsigned short* __restrict__ xbf) {
  int row = blockIdx.x, t = threadIdx.x;
  int e0 = ti[row * 2], e1 = ti[row * 2 + 1];
  int p0 = slot[row * 2], p1 = slot[row * 2 + 1];
  float w0 = tw[row * 2], w1 = tw[row * 2 + 1];
  const float* y0 = ye + ((size_t)e0 * SQ + p0) * DM;
  const float* y1 = ye + ((size_t)e1 * SQ + p1) * DM;
  const float* xi = xin + (size_t)row * DM;
  float v[3]; float s = 0.f, sq = 0.f;
  #pragma unroll
  for (int i = 0; i < 3; ++i) {
    int idx = t + i * 256;
    v[i] = xi[idx] + w0 * y0[idx] + w1 * y1[idx];
    s += v[i]; sq += v[i] * v[i];
  }
  #pragma unroll
  for (int o = 32; o; o >>= 1) { s += __shfl_xor(s, o); sq += __shfl_xor(sq, o); }
  __shared__ float rsm[4], rqm[4];
  int wv = t >> 6;
  if ((t & 63) == 0) { rsm[wv] = s; rqm[wv] = sq; }
  __syncthreads();
  s = rsm[0] + rsm[1] + rsm[2] + rsm[3];
  sq = rqm[0] + rqm[1] + rqm[2] + rqm[3];
  float mean = s * (1.f / 768.f);
  float var = sq * (1.f / 768.f) - mean * mean;
  float inv = rsqrtf(var + 1e-5f);
  float* xo = xout + (size_t)row * DM;
  unsigned short* xb = xbf + (size_t)row * DM;
  #pragma unroll
  for (int i = 0; i < 3; ++i) {
    int idx = t + i * 256;
    float y = (v[i] - mean) * inv * w[idx] + b[idx];
    xo[idx] = y; xb[idx] = f2bf(y);
  }
}

// ---------------- final RMSNorm -> bf16 ----------------
__global__ __launch_bounds__(256) void rms_k(const float* __restrict__ x,
    const float* __restrict__ rw, unsigned short* __restrict__ xbf) {
  int row = blockIdx.x, t = threadIdx.x;
  const float* xi = x + (size_t)row * DM;
  float v[3]; float sq = 0.f;
  #pragma unroll
  for (int i = 0; i < 3; ++i) {
    int idx = t + i * 256;
    v[i] = xi[idx];
    sq += v[i] * v[i];
  }
  #pragma unroll
  for (int o = 32; o; o >>= 1) sq += __shfl_xor(sq, o);
  __shared__ float rqm[4];
  int wv = t >> 6;
  if ((t & 63) == 0) rqm[wv] = sq;
  __syncthreads();
  sq = rqm[0] + rqm[1] + rqm[2] + rqm[3];
  float inv = rsqrtf(sq * (1.f / 768.f) + 1.1920929e-07f);
  unsigned short* xb = xbf + (size_t)row * DM;
  #pragma unroll
  for (int i = 0; i < 3; ++i) {
    int idx = t + i * 256;
    xb[idx] = f2bf(v[i] * inv * rw[idx]);
  }
}

// ================= host =================
extern "C" void kernel_launch(void* const* d_in, const int* in_sizes, int n_in,
                              void* d_out, int out_size, void* d_ws, size_t ws_size,
                              hipStream_t stream) {
  (void)in_sizes; (void)n_in; (void)out_size; (void)ws_size;
  const int*   tokens = (const int*)d_in[0];
  const float* emb    = (const float*)d_in[1];
  const float* qkv_w  = (const float*)d_in[2];
  const float* qkv_b  = (const float*)d_in[3];
  const float* out_w  = (const float*)d_in[4];
  const float* out_b  = (const float*)d_in[5];
  const float* ln1_w  = (const float*)d_in[6];
  const float* ln1_b  = (const float*)d_in[7];
  const float* ln2_w  = (const float*)d_in[8];
  const float* ln2_b  = (const float*)d_in[9];
  const float* gate_w = (const float*)d_in[10];
  const float* eg_w   = (const float*)d_in[11];
  const float* eu_w   = (const float*)d_in[12];
  const float* ed_w   = (const float*)d_in[13];
  const float* rms_w  = (const float*)d_in[14];
  float* out = (float*)d_out;

  char* wsb = (char*)d_ws;
  float*          x_f    = (float*)(wsb + 0);                   // 6291456 B
  unsigned short* x_bf   = (unsigned short*)(wsb + 6291456);    // 3145728
  unsigned short* qkv_bf = (unsigned short*)(wsb + 9437184);    // 9437184
  unsigned short* vt     = (unsigned short*)(wsb + 18874368);   // 3145728
  unsigned short* o_bf   = (unsigned short*)(wsb + 22020096);   // 3145728
  float*          tmp_f  = (float*)(wsb + 25165824);            // 6291456
  float*          tw     = (float*)(wsb + 31457280);            // 16384
  int*            ti     = (int*)(wsb + 31473664);              // 16384
  int*            cnt    = (int*)(wsb + 31490048);              // 256
  int*            lists  = (int*)(wsb + 31490304);              // 65536
  int*            slot   = (int*)(wsb + 31555840);              // 16384
  // big union region @ 31572224: scores(100663296) | hg(50331648)+hu(50331648), ye after
  unsigned short* scores = (unsigned short*)(wsb + 31572224);
  unsigned short* hg     = (unsigned short*)(wsb + 31572224);
  unsigned short* hu     = (unsigned short*)(wsb + 31572224 + 50331648);
  float*          ye     = (float*)(wsb + 31572224 + 100663296);

  embed_k<<<SQ * DM / 256, 256, 0, stream>>>(tokens, emb, x_f, x_bf);

  for (int l = 0; l < NL; ++l) {
    const float* qw = qkv_w + (size_t)l * 3 * DM * DM;
    const float* qb = qkv_b + (size_t)l * 3 * DM;
    const float* ow = out_w + (size_t)l * DM * DM;
    const float* ob = out_b + (size_t)l * DM;
    const float* gw = gate_w + (size_t)l * NE * DM;
    const float* egw = eg_w + (size_t)l * NE * FF * DM;
    const float* euw = eu_w + (size_t)l * NE * FF * DM;
    const float* edw = ed_w + (size_t)l * NE * DM * FF;

    // qkv = x @ qkv_w^T + b  -> bf16   (mT=16, nT=18)
    gemm_k<false, false, true, true><<<16 * 18, 256, 0, stream>>>(
        x_bf, DM, 0, qw, DM, 0, qb, qkv_bf, 3 * DM, 0,
        SQ, 3 * DM, DM, 1.f, nullptr, 0, nullptr, 16, 18);

    transpose_v_k<<<dim3(SQ / 64, NHD), 256, 0, stream>>>(qkv_bf, vt);

    // scores[h] = (Q_h @ K_h^T) / 8  -> bf16   (mT=16, nT=16, z=12)
    gemm_k<true, false, false, true><<<16 * 16 * NHD, 256, 0, stream>>>(
        qkv_bf, 3 * DM, DHD, qkv_bf + DM, 3 * DM, DHD, nullptr,
        scores, SQ, (long long)SQ * SQ,
        SQ, SQ, DHD, 0.125f, nullptr, 0, nullptr, 16, 16);

    softmax_k<<<NHD * SQ, 256, 0, stream>>>(scores);

    // o[:, h*64:] = P_h @ V_h  (mT=16, nT=1, z=12)
    gemm_k<true, false, false, true><<<16 * 1 * NHD, 256, 0, stream>>>(
        scores, SQ, (long long)SQ * SQ, vt, SQ, (long long)DHD * SQ, nullptr,
        o_bf, DM, DHD,
        SQ, DHD, SQ, 1.f, nullptr, 0, nullptr, 16, 1);

    // attn out-proj -> tmp_f (fp32)   (mT=16, nT=6)
    gemm_k<false, false, true, false><<<16 * 6, 256, 0, stream>>>(
        o_bf, DM, 0, ow, DM, 0, ob, tmp_f, DM, 0,
        SQ, DM, DM, 1.f, nullptr, 0, nullptr, 16, 6);

    add_ln_k<<<SQ, 256, 0, stream>>>(x_f, tmp_f, ln1_w + l * DM, ln1_b + l * DM,
                                     x_f, x_bf);

    zero_k<<<1, 64, 0, stream>>>(cnt);
    gate_topk_k<<<SQ, 64, 0, stream>>>(x_f, gw, tw, ti, cnt, lists, slot);

    // expert up/gate GEMMs (gathered rows, M = cnt[e])  (mT=16, nT=12, z=8)
    gemm_k<false, true, false, true><<<16 * 12 * NE, 256, 0, stream>>>(
        x_bf, DM, 0, egw, DM, (long long)FF * DM, nullptr,
        hg, FF, (long long)SQ * FF,
        SQ, FF, DM, 1.f, lists, SQ, cnt, 16, 12);
    gemm_k<false, true, false, true><<<16 * 12 * NE, 256, 0, stream>>>(
        x_bf, DM, 0, euw, DM, (long long)FF * DM, nullptr,
        hu, FF, (long long)SQ * FF,
        SQ, FF, DM, 1.f, lists, SQ, cnt, 16, 12);

    silu_mul_k<<<dim3(SQ, NE), 256, 0, stream>>>(hg, hu, cnt);

    // ye = hh @ ed^T (fp32 out)   (mT=16, nT=6, z=8)
    gemm_k<false, false, false, false><<<16 * 6 * NE, 256, 0, stream>>>(
        hg, FF, (long long)SQ * FF, edw, FF, (long long)DM * FF, nullptr,
        ye, DM, (long long)SQ * DM,
        SQ, DM, FF, 1.f, nullptr, 0, cnt, 16, 6);

    combine_ln_k<<<SQ, 256, 0, stream>>>(x_f, ye, tw, ti, slot,
                                         ln2_w + l * DM, ln2_b + l * DM,
                                         x_f, x_bf);
  }

  rms_k<<<SQ, 256, 0, stream>>>(x_f, rms_w, x_bf);

  // logits = xn @ emb^T (fp32 out)   (mT=16, nT=250)
  gemm_k<false, false, false, false><<<16 * 250, 256, 0, stream>>>(
      x_bf, DM, 0, emb, DM, 0, nullptr, out, NV, 0,
      SQ, NV, DM, 1.f, nullptr, 0, nullptr, 16, 250);
}

// Round 3
// 1011.664 us; speedup vs baseline: 1.1255x; 1.1255x over previous
//
#include <hip/hip_runtime.h>

// ---- problem dims ----
#define SQ   2048
#define DM   768
#define NHD  12
#define DHD  64
#define FF   1536
#define NE   8
#define NL   2
#define NV   32000

typedef __attribute__((ext_vector_type(8))) short bf16x8;
typedef __attribute__((ext_vector_type(4))) float f32x4;

__device__ __forceinline__ unsigned short f2bf(float f) {
  unsigned u = __float_as_uint(f);
  return (unsigned short)((u + 0x7fffu + ((u >> 16) & 1u)) >> 16);
}
__device__ __forceinline__ float bf2f(unsigned short h) {
  return __uint_as_float(((unsigned)h) << 16);
}

// async global->LDS, 16B per lane; dest = wave-uniform base + lane*16
#define GLD16(ldsp, gp) __builtin_amdgcn_global_load_lds( \
    (const __attribute__((address_space(1))) void*)(gp),  \
    (__attribute__((address_space(3))) void*)(ldsp), 16, 0, 0)

// ---------------- fp32 -> bf16 bulk convert (n must be /8, grid = n/8/256) ----
__global__ __launch_bounds__(256) void conv_k(const float* __restrict__ s,
    unsigned short* __restrict__ d) {
  size_t i = (size_t)(blockIdx.x * 256 + threadIdx.x) * 8;
  float4 a = *(const float4*)(s + i);
  float4 b = *(const float4*)(s + i + 4);
  int4 pk = make_int4(
      (int)((unsigned)f2bf(a.x) | ((unsigned)f2bf(a.y) << 16)),
      (int)((unsigned)f2bf(a.z) | ((unsigned)f2bf(a.w) << 16)),
      (int)((unsigned)f2bf(b.x) | ((unsigned)f2bf(b.y) << 16)),
      (int)((unsigned)f2bf(b.z) | ((unsigned)f2bf(b.w) << 16)));
  *(int4*)(d + i) = pk;
}

// ---------------- embedding: x = emb[tok]*sqrt(D) ----------------
__global__ __launch_bounds__(256) void embed_k(const int* __restrict__ tok,
    const float* __restrict__ emb, float* __restrict__ x,
    unsigned short* __restrict__ xbf) {
  int idx = blockIdx.x * 256 + threadIdx.x;   // < 2048*768
  int s = idx / DM, d = idx % DM;
  float v = emb[(size_t)tok[s] * DM + d] * 27.712812921102035f;
  x[idx] = v;
  xbf[idx] = f2bf(v);
}

// ---------------- bf16 MFMA GEMM, m97 structure ----------------
// global_load_lds(16B) staging, linear LDS, XOR-swizzled per-lane source.
// 1-D grid, XCD-chunked bijective swizzle, z-fastest/m-middle/n-outer decode.
// C[z][m][n] = scale * sum_k A[z][row(m)][k] * B[z][n][k] (+ bias[n])
template<bool GATHER, bool BIAS, bool OBF16>
__global__ __launch_bounds__(256) void gemm_k(
    const unsigned short* __restrict__ A, long long lda, long long a_z,
    const unsigned short* __restrict__ B, long long ldb, long long b_z,
    const float* __restrict__ bias,
    void* __restrict__ C, long long ldc, long long c_z,
    int M, int N, int Kd, float scale,
    const int* __restrict__ glist, long long gl_z,
    const int* __restrict__ cnt, int mT, int nT, int Z)
{
  // bijective XCD-chunked swizzle (m204)
  int nwg = gridDim.x, bid = blockIdx.x;
  int q = nwg >> 3, r = nwg & 7;
  int xcd = bid & 7, j = bid >> 3;
  int wid = (xcd < r ? xcd * (q + 1) : r * (q + 1) + (xcd - r) * q) + j;
  // z fastest (balance), m middle (A stride), n outer (B-panel reuse per chunk)
  int z = wid % Z; int rem = wid / Z;
  int mt = rem % mT, nt = rem / mT;

  int Mz = cnt ? cnt[z] : M;
  int m0 = mt * 128, n0 = nt * 128;
  if (m0 >= Mz) return;

  const unsigned short* Ab = A + (size_t)z * a_z;
  const unsigned short* Bb = B + (size_t)z * b_z;

  __shared__ __align__(16) unsigned short As[128 * 64];
  __shared__ __align__(16) unsigned short Bs[128 * 64];

  int t = threadIdx.x, w = t >> 6, lane = t & 63;
  int wm = (w >> 1) * 64, wn = (w & 1) * 64;
  int fr = lane & 15, ksg = lane >> 4;
  int lrow = lane >> 3;                      // 0..7 within 8-row stripe
  int lchunk = ((lane & 7) ^ lrow) * 8;      // element offset of 16B chunk

  // per-lane staging source pointers (hoisted; k0 added in loop)
  const unsigned short* ap[4];
  const unsigned short* bp[4];
  unsigned short* la[4];
  unsigned short* lb[4];
  #pragma unroll
  for (int i = 0; i < 4; ++i) {
    int rrow = w * 32 + i * 8 + lrow;
    int gr = m0 + rrow; if (gr >= Mz) gr = Mz - 1;
    int arow; if constexpr (GATHER) arow = glist[(size_t)z * gl_z + gr]; else arow = gr;
    ap[i] = Ab + (size_t)arow * lda + lchunk;
    int br = n0 + rrow; if (br >= N) br = N - 1;
    bp[i] = Bb + (size_t)br * ldb + lchunk;
    la[i] = &As[(w * 32 + i * 8) * 64];
    lb[i] = &Bs[(w * 32 + i * 8) * 64];
  }

  // read-side swizzled chunk offsets (elements), row-phase = fr&7
  int rx = fr & 7;
  int off0 = ((0 + ksg) ^ rx) * 8;   // kb=0 slot
  int off1 = ((4 + ksg) ^ rx) * 8;   // kb=1 slot

  f32x4 acc[4][4] = {};

  for (int k0 = 0; k0 < Kd; k0 += 64) {
    #pragma unroll
    for (int i = 0; i < 4; ++i) GLD16(la[i], ap[i] + k0);
    #pragma unroll
    for (int i = 0; i < 4; ++i) GLD16(lb[i], bp[i] + k0);
    __syncthreads();
    #pragma unroll
    for (int kb = 0; kb < 2; ++kb) {
      int offk = kb ? off1 : off0;
      bf16x8 af[4], bv[4];
      #pragma unroll
      for (int m = 0; m < 4; ++m)
        af[m] = *(const bf16x8*)&As[(wm + m * 16 + fr) * 64 + offk];
      #pragma unroll
      for (int n = 0; n < 4; ++n)
        bv[n] = *(const bf16x8*)&Bs[(wn + n * 16 + fr) * 64 + offk];
      #pragma unroll
      for (int m = 0; m < 4; ++m)
        #pragma unroll
        for (int n = 0; n < 4; ++n)
          acc[m][n] = __builtin_amdgcn_mfma_f32_16x16x32_bf16(
              af[m], bv[n], acc[m][n], 0, 0, 0);
    }
    __syncthreads();
  }

  // epilogue: C/D layout col=lane&15, row=(lane>>4)*4+reg
  int rb = ksg * 4;
  #pragma unroll
  for (int m = 0; m < 4; ++m) {
    #pragma unroll
    for (int n = 0; n < 4; ++n) {
      int col = n0 + wn + n * 16 + fr;
      if (col >= N) continue;
      #pragma unroll
      for (int rr = 0; rr < 4; ++rr) {
        int row = m0 + wm + m * 16 + rb + rr;
        if (row >= Mz) continue;
        float v = acc[m][n][rr] * scale;
        if constexpr (BIAS) v += bias[col];
        size_t off = (size_t)z * c_z + (size_t)row * ldc + col;
        if constexpr (OBF16) ((unsigned short*)C)[off] = f2bf(v);
        else                 ((float*)C)[off] = v;
      }
    }
  }
}

// ---------------- V transpose: vt[h][d][k] = qkv[k][2D + h*64 + d] ----------------
__global__ __launch_bounds__(256) void transpose_v_k(
    const unsigned short* __restrict__ qkv, unsigned short* __restrict__ vt) {
  int kt = blockIdx.x;   // 0..31
  int h  = blockIdx.y;   // 0..11
  __shared__ unsigned short tile[64][72];
  int t = threadIdx.x;
  int r = t >> 2;             // 0..63
  int c0 = (t & 3) * 16;      // 0,16,32,48
  const unsigned short* src =
      qkv + (size_t)(kt * 64 + r) * (3 * DM) + 2 * DM + h * DHD + c0;
  *(int4*)&tile[r][c0]     = *(const int4*)(src);
  *(int4*)&tile[r][c0 + 8] = *(const int4*)(src + 8);
  __syncthreads();
  unsigned u[8];
  #pragma unroll
  for (int j = 0; j < 8; ++j)
    u[j] = (unsigned)tile[c0 + 2 * j][r] | ((unsigned)tile[c0 + 2 * j + 1][r] << 16);
  unsigned short* dst = vt + (size_t)(h * DHD + r) * SQ + kt * 64 + c0;
  *(int4*)dst       = make_int4((int)u[0], (int)u[1], (int)u[2], (int)u[3]);
  *(int4*)(dst + 8) = make_int4((int)u[4], (int)u[5], (int)u[6], (int)u[7]);
}

// ---------------- softmax over one score row (2048, bf16, in-place) ----------------
__global__ __launch_bounds__(256) void softmax_k(unsigned short* __restrict__ sc) {
  unsigned short* p = sc + (size_t)blockIdx.x * SQ;
  int t = threadIdx.x;
  int4 raw = ((int4*)p)[t];
  unsigned short* h = (unsigned short*)&raw;
  float f[8];
  float mx = -1e30f;
  #pragma unroll
  for (int j = 0; j < 8; ++j) { f[j] = bf2f(h[j]); mx = fmaxf(mx, f[j]); }
  #pragma unroll
  for (int o = 32; o; o >>= 1) mx = fmaxf(mx, __shfl_xor(mx, o));
  __shared__ float rm[4], rs[4];
  int w = t >> 6;
  if ((t & 63) == 0) rm[w] = mx;
  __syncthreads();
  mx = fmaxf(fmaxf(rm[0], rm[1]), fmaxf(rm[2], rm[3]));
  float s = 0.f;
  #pragma unroll
  for (int j = 0; j < 8; ++j) { f[j] = expf(f[j] - mx); s += f[j]; }
  #pragma unroll
  for (int o = 32; o; o >>= 1) s += __shfl_xor(s, o);
  if ((t & 63) == 0) rs[w] = s;
  __syncthreads();
  s = rs[0] + rs[1] + rs[2] + rs[3];
  float inv = 1.f / s;
  #pragma unroll
  for (int j = 0; j < 8; ++j) h[j] = f2bf(f[j] * inv);
  ((int4*)p)[t] = raw;
}

// ---------------- x = LN(x + add) ----------------
__global__ __launch_bounds__(256) void add_ln_k(const float* __restrict__ xin,
    const float* __restrict__ add, const float* __restrict__ w,
    const float* __restrict__ b, float* __restrict__ xout,
    unsigned short* __restrict__ xbf) {
  int row = blockIdx.x, t = threadIdx.x;
  const float* xi = xin + (size_t)row * DM;
  const float* ai = add + (size_t)row * DM;
  float v[3]; float s = 0.f, sq = 0.f;
  #pragma unroll
  for (int i = 0; i < 3; ++i) {
    int idx = t + i * 256;
    v[i] = xi[idx] + ai[idx];
    s += v[i]; sq += v[i] * v[i];
  }
  #pragma unroll
  for (int o = 32; o; o >>= 1) { s += __shfl_xor(s, o); sq += __shfl_xor(sq, o); }
  __shared__ float rsm[4], rqm[4];
  int wv = t >> 6;
  if ((t & 63) == 0) { rsm[wv] = s; rqm[wv] = sq; }
  __syncthreads();
  s = rsm[0] + rsm[1] + rsm[2] + rsm[3];
  sq = rqm[0] + rqm[1] + rqm[2] + rqm[3];
  float mean = s * (1.f / 768.f);
  float var = sq * (1.f / 768.f) - mean * mean;
  float inv = rsqrtf(var + 1e-5f);
  float* xo = xout + (size_t)row * DM;
  unsigned short* xb = xbf + (size_t)row * DM;
  #pragma unroll
  for (int i = 0; i < 3; ++i) {
    int idx = t + i * 256;
    float y = (v[i] - mean) * inv * w[idx] + b[idx];
    xo[idx] = y; xb[idx] = f2bf(y);
  }
}

// ---------------- gate: 8 dots, top-2, softmax, expert bucket lists ----------------
__global__ void gate_topk_k(const float* __restrict__ x, const float* __restrict__ gw,
    float* __restrict__ tw, int* __restrict__ ti, int* __restrict__ cnt,
    int* __restrict__ lists, int* __restrict__ slot) {
  int sIdx = blockIdx.x, lane = threadIdx.x;  // 64 threads
  const float* xr = x + (size_t)sIdx * DM;
  float acc[NE] = {};
  for (int d = lane; d < DM; d += 64) {
    float xv = xr[d];
    #pragma unroll
    for (int e = 0; e < NE; ++e) acc[e] += xv * gw[e * DM + d];
  }
  #pragma unroll
  for (int e = 0; e < NE; ++e) {
    #pragma unroll
    for (int o = 32; o; o >>= 1) acc[e] += __shfl_down(acc[e], o);
  }
  if (lane == 0) {
    float v0 = -1e30f, v1 = -1e30f; int i0 = 0, i1 = 0;
    #pragma unroll
    for (int e = 0; e < NE; ++e) {
      float v = acc[e];
      if (v > v0) { v1 = v0; i1 = i0; v0 = v; i0 = e; }
      else if (v > v1) { v1 = v; i1 = e; }
    }
    float e1 = expf(v1 - v0);
    float inv = 1.f / (1.f + e1);
    tw[sIdx * 2] = inv; tw[sIdx * 2 + 1] = e1 * inv;
    ti[sIdx * 2] = i0;  ti[sIdx * 2 + 1] = i1;
    int p0 = atomicAdd(&cnt[i0], 1); lists[i0 * SQ + p0] = sIdx; slot[sIdx * 2] = p0;
    int p1 = atomicAdd(&cnt[i1], 1); lists[i1 * SQ + p1] = sIdx; slot[sIdx * 2 + 1] = p1;
  }
}

__global__ void zero_k(int* __restrict__ c) {
  if (threadIdx.x < NE) c[threadIdx.x] = 0;
}

// ---------------- hh = silu(hg) * hu (in-place into hg) ----------------
__global__ __launch_bounds__(256) void silu_mul_k(unsigned short* __restrict__ hg,
    const unsigned short* __restrict__ hu, const int* __restrict__ cnt) {
  int e = blockIdx.y, sl = blockIdx.x;
  if (sl >= cnt[e]) return;
  size_t base = ((size_t)e * SQ + sl) * FF;
  int t = threadIdx.x;
  #pragma unroll
  for (int i = 0; i < FF / 256; ++i) {
    size_t idx = base + t + i * 256;
    float g = bf2f(hg[idx]);
    float u = bf2f(hu[idx]);
    float sv = g / (1.f + expf(-g));
    hg[idx] = f2bf(sv * u);
  }
}

// ---------------- moe combine + LN ----------------
__global__ __launch_bounds__(256) void combine_ln_k(const float* __restrict__ xin,
    const float* __restrict__ ye, const float* __restrict__ tw,
    const int* __restrict__ ti, const int* __restrict__ slot,
    const float* __restrict__ w, const float* __restrict__ b,
    float* __restrict__ xout, unsigned short* __restrict__ xbf) {
  int row = blockIdx.x, t = threadIdx.x;
  int e0 = ti[row * 2], e1 = ti[row * 2 + 1];
  int p0 = slot[row * 2], p1 = slot[row * 2 + 1];
  float w0 = tw[row * 2], w1 = tw[row * 2 + 1];
  const float* y0 = ye + ((size_t)e0 * SQ + p0) * DM;
  const float* y1 = ye + ((size_t)e1 * SQ + p1) * DM;
  const float* xi = xin + (size_t)row * DM;
  float v[3]; float s = 0.f, sq = 0.f;
  #pragma unroll
  for (int i = 0; i < 3; ++i) {
    int idx = t + i * 256;
    v[i] = xi[idx] + w0 * y0[idx] + w1 * y1[idx];
    s += v[i]; sq += v[i] * v[i];
  }
  #pragma unroll
  for (int o = 32; o; o >>= 1) { s += __shfl_xor(s, o); sq += __shfl_xor(sq, o); }
  __shared__ float rsm[4], rqm[4];
  int wv = t >> 6;
  if ((t & 63) == 0) { rsm[wv] = s; rqm[wv] = sq; }
  __syncthreads();
  s = rsm[0] + rsm[1] + rsm[2] + rsm[3];
  sq = rqm[0] + rqm[1] + rqm[2] + rqm[3];
  float mean = s * (1.f / 768.f);
  float var = sq * (1.f / 768.f) - mean * mean;
  float inv = rsqrtf(var + 1e-5f);
  float* xo = xout + (size_t)row * DM;
  unsigned short* xb = xbf + (size_t)row * DM;
  #pragma unroll
  for (int i = 0; i < 3; ++i) {
    int idx = t + i * 256;
    float y = (v[i] - mean) * inv * w[idx] + b[idx];
    xo[idx] = y; xb[idx] = f2bf(y);
  }
}

// ---------------- final RMSNorm -> bf16 ----------------
__global__ __launch_bounds__(256) void rms_k(const float* __restrict__ x,
    const float* __restrict__ rw, unsigned short* __restrict__ xbf) {
  int row = blockIdx.x, t = threadIdx.x;
  const float* xi = x + (size_t)row * DM;
  float v[3]; float sq = 0.f;
  #pragma unroll
  for (int i = 0; i < 3; ++i) {
    int idx = t + i * 256;
    v[i] = xi[idx];
    sq += v[i] * v[i];
  }
  #pragma unroll
  for (int o = 32; o; o >>= 1) sq += __shfl_xor(sq, o);
  __shared__ float rqm[4];
  int wv = t >> 6;
  if ((t & 63) == 0) rqm[wv] = sq;
  __syncthreads();
  sq = rqm[0] + rqm[1] + rqm[2] + rqm[3];
  float inv = rsqrtf(sq * (1.f / 768.f) + 1.1920929e-07f);
  unsigned short* xb = xbf + (size_t)row * DM;
  #pragma unroll
  for (int i = 0; i < 3; ++i) {
    int idx = t + i * 256;
    xb[idx] = f2bf(v[i] * inv * rw[idx]);
  }
}

// ================= host =================
extern "C" void kernel_launch(void* const* d_in, const int* in_sizes, int n_in,
                              void* d_out, int out_size, void* d_ws, size_t ws_size,
                              hipStream_t stream) {
  (void)in_sizes; (void)n_in; (void)out_size; (void)ws_size;
  const int*   tokens = (const int*)d_in[0];
  const float* emb    = (const float*)d_in[1];
  const float* qkv_w  = (const float*)d_in[2];
  const float* qkv_b  = (const float*)d_in[3];
  const float* out_w  = (const float*)d_in[4];
  const float* out_b  = (const float*)d_in[5];
  const float* ln1_w  = (const float*)d_in[6];
  const float* ln1_b  = (const float*)d_in[7];
  const float* ln2_w  = (const float*)d_in[8];
  const float* ln2_b  = (const float*)d_in[9];
  const float* gate_w = (const float*)d_in[10];
  const float* eg_w   = (const float*)d_in[11];
  const float* eu_w   = (const float*)d_in[12];
  const float* ed_w   = (const float*)d_in[13];
  const float* rms_w  = (const float*)d_in[14];
  float* out = (float*)d_out;

  char* wsb = (char*)d_ws;
  float*          x_f    = (float*)(wsb + 0);                   // 6291456
  unsigned short* x_bf   = (unsigned short*)(wsb + 6291456);    // 3145728
  unsigned short* qkv_bf = (unsigned short*)(wsb + 9437184);    // 9437184
  unsigned short* vt     = (unsigned short*)(wsb + 18874368);   // 3145728
  unsigned short* o_bf   = (unsigned short*)(wsb + 22020096);   // 3145728
  float*          tmp_f  = (float*)(wsb + 25165824);            // 6291456
  float*          tw     = (float*)(wsb + 31457280);            // 16384
  int*            ti     = (int*)(wsb + 31473664);              // 16384
  int*            cnt    = (int*)(wsb + 31490048);              // 256
  int*            lists  = (int*)(wsb + 31490304);              // 65536
  int*            slot   = (int*)(wsb + 31555840);              // 16384
  unsigned short* emb_bf = (unsigned short*)(wsb + 31572224);   // 49152000
  unsigned short* wbf    = (unsigned short*)(wsb + 80724224);   // 61341696
  // union @142065920: scores(100663296) | hg(50331648)+hu(50331648); ye = hu region
  unsigned short* scores = (unsigned short*)(wsb + 142065920);
  unsigned short* hg     = (unsigned short*)(wsb + 142065920);
  unsigned short* hu     = (unsigned short*)(wsb + 142065920 + 50331648);
  float*          ye     = (float*)(wsb + 142065920 + 50331648); // overlaps hu (hu dead)

  // wbf sublayout (ushort element offsets)
  unsigned short* qw_bf = wbf;                 // 1769472
  unsigned short* ow_bf = wbf + 1769472;       // 589824
  unsigned short* eg_bf = wbf + 2359296;       // 9437184
  unsigned short* eu_bf = wbf + 11796480;      // 9437184
  unsigned short* ed_bf = wbf + 21233664;      // 9437184

  conv_k<<<12000, 256, 0, stream>>>(emb, emb_bf);               // 24576000 elems
  embed_k<<<SQ * DM / 256, 256, 0, stream>>>(tokens, emb, x_f, x_bf);

  for (int l = 0; l < NL; ++l) {
    const float* qw = qkv_w + (size_t)l * 3 * DM * DM;
    const float* qb = qkv_b + (size_t)l * 3 * DM;
    const float* ow = out_w + (size_t)l * DM * DM;
    const float* ob = out_b + (size_t)l * DM;
    const float* gw = gate_w + (size_t)l * NE * DM;
    const float* egw = eg_w + (size_t)l * NE * FF * DM;
    const float* euw = eu_w + (size_t)l * NE * FF * DM;
    const float* edw = ed_w + (size_t)l * NE * DM * FF;

    // weight conversion for this layer
    conv_k<<<864, 256, 0, stream>>>(qw, qw_bf);
    conv_k<<<288, 256, 0, stream>>>(ow, ow_bf);
    conv_k<<<4608, 256, 0, stream>>>(egw, eg_bf);
    conv_k<<<4608, 256, 0, stream>>>(euw, eu_bf);
    conv_k<<<4608, 256, 0, stream>>>(edw, ed_bf);

    // qkv = x @ qkv_w^T + b  -> bf16   (mT=16, nT=18, Z=1)
    gemm_k<false, true, true><<<16 * 18, 256, 0, stream>>>(
        x_bf, DM, 0, qw_bf, DM, 0, qb, qkv_bf, 3 * DM, 0,
        SQ, 3 * DM, DM, 1.f, nullptr, 0, nullptr, 16, 18, 1);

    transpose_v_k<<<dim3(SQ / 64, NHD), 256, 0, stream>>>(qkv_bf, vt);

    // scores[h] = (Q_h @ K_h^T) / 8  -> bf16   (mT=16, nT=16, Z=12)
    gemm_k<false, false, true><<<16 * 16 * NHD, 256, 0, stream>>>(
        qkv_bf, 3 * DM, DHD, qkv_bf + DM, 3 * DM, DHD, nullptr,
        scores, SQ, (long long)SQ * SQ,
        SQ, SQ, DHD, 0.125f, nullptr, 0, nullptr, 16, 16, NHD);

    softmax_k<<<NHD * SQ, 256, 0, stream>>>(scores);

    // o[:, h*64:] = P_h @ V_h  (mT=16, nT=1, Z=12)
    gemm_k<false, false, true><<<16 * 1 * NHD, 256, 0, stream>>>(
        scores, SQ, (long long)SQ * SQ, vt, SQ, (long long)DHD * SQ, nullptr,
        o_bf, DM, DHD,
        SQ, DHD, SQ, 1.f, nullptr, 0, nullptr, 16, 1, NHD);

    // attn out-proj -> tmp_f (fp32)   (mT=16, nT=6, Z=1)
    gemm_k<false, true, false><<<16 * 6, 256, 0, stream>>>(
        o_bf, DM, 0, ow_bf, DM, 0, ob, tmp_f, DM, 0,
        SQ, DM, DM, 1.f, nullptr, 0, nullptr, 16, 6, 1);

    add_ln_k<<<SQ, 256, 0, stream>>>(x_f, tmp_f, ln1_w + l * DM, ln1_b + l * DM,
                                     x_f, x_bf);

    zero_k<<<1, 64, 0, stream>>>(cnt);
    gate_topk_k<<<SQ, 64, 0, stream>>>(x_f, gw, tw, ti, cnt, lists, slot);

    // expert up/gate GEMMs (gathered rows, M = cnt[e])  (mT=16, nT=12, Z=8)
    gemm_k<true, false, true><<<16 * 12 * NE, 256, 0, stream>>>(
        x_bf, DM, 0, eg_bf, DM, (long long)FF * DM, nullptr,
        hg, FF, (long long)SQ * FF,
        SQ, FF, DM, 1.f, lists, SQ, cnt, 16, 12, NE);
    gemm_k<true, false, true><<<16 * 12 * NE, 256, 0, stream>>>(
        x_bf, DM, 0, eu_bf, DM, (long long)FF * DM, nullptr,
        hu, FF, (long long)SQ * FF,
        SQ, FF, DM, 1.f, lists, SQ, cnt, 16, 12, NE);

    silu_mul_k<<<dim3(SQ, NE), 256, 0, stream>>>(hg, hu, cnt);

    // ye = hh @ ed^T (fp32 out)   (mT=16, nT=6, Z=8)  [ye overlaps dead hu]
    gemm_k<false, false, false><<<16 * 6 * NE, 256, 0, stream>>>(
        hg, FF, (long long)SQ * FF, ed_bf, FF, (long long)DM * FF, nullptr,
        ye, DM, (long long)SQ * DM,
        SQ, DM, FF, 1.f, nullptr, 0, cnt, 16, 6, NE);

    combine_ln_k<<<SQ, 256, 0, stream>>>(x_f, ye, tw, ti, slot,
                                         ln2_w + l * DM, ln2_b + l * DM,
                                         x_f, x_bf);
  }

  rms_k<<<SQ, 256, 0, stream>>>(x_f, rms_w, x_bf);

  // logits = xn @ emb_bf^T (fp32 out)   (mT=16, nT=250, Z=1)
  gemm_k<false, false, false><<<16 * 250, 256, 0, stream>>>(
      x_bf, DM, 0, emb_bf, DM, 0, nullptr, out, NV, 0,
      SQ, NV, DM, 1.f, nullptr, 0, nullptr, 16, 250, 1);
}

// Round 4
// 847.537 us; speedup vs baseline: 1.3434x; 1.1937x over previous
//
#include <hip/hip_runtime.h>

// ---- problem dims ----
#define SQ   2048
#define DM   768
#define NHD  12
#define DHD  64
#define FF   1536
#define NE   8
#define NL   2
#define NV   32000

typedef __attribute__((ext_vector_type(8))) short bf16x8;
typedef __attribute__((ext_vector_type(4))) float f32x4;

__device__ __forceinline__ unsigned short f2bf(float f) {
  unsigned u = __float_as_uint(f);
  return (unsigned short)((u + 0x7fffu + ((u >> 16) & 1u)) >> 16);
}
__device__ __forceinline__ float bf2f(unsigned short h) {
  return __uint_as_float(((unsigned)h) << 16);
}

// async global->LDS, 16B per lane; dest = wave-uniform base + lane*16
#define GLD16(ldsp, gp) __builtin_amdgcn_global_load_lds( \
    (const __attribute__((address_space(1))) void*)(gp),  \
    (__attribute__((address_space(3))) void*)(ldsp), 16, 0, 0)

// ---------------- fp32 -> bf16 bulk convert (n must be /8, grid = n/8/256) ----
__global__ __launch_bounds__(256) void conv_k(const float* __restrict__ s,
    unsigned short* __restrict__ d) {
  size_t i = (size_t)(blockIdx.x * 256 + threadIdx.x) * 8;
  float4 a = *(const float4*)(s + i);
  float4 b = *(const float4*)(s + i + 4);
  int4 pk = make_int4(
      (int)((unsigned)f2bf(a.x) | ((unsigned)f2bf(a.y) << 16)),
      (int)((unsigned)f2bf(a.z) | ((unsigned)f2bf(a.w) << 16)),
      (int)((unsigned)f2bf(b.x) | ((unsigned)f2bf(b.y) << 16)),
      (int)((unsigned)f2bf(b.z) | ((unsigned)f2bf(b.w) << 16)));
  *(int4*)(d + i) = pk;
}

// ---------------- embedding: x = emb[tok]*sqrt(D) ----------------
__global__ __launch_bounds__(256) void embed_k(const int* __restrict__ tok,
    const float* __restrict__ emb, float* __restrict__ x,
    unsigned short* __restrict__ xbf) {
  int idx = blockIdx.x * 256 + threadIdx.x;   // < 2048*768
  int s = idx / DM, d = idx % DM;
  float v = emb[(size_t)tok[s] * DM + d] * 27.712812921102035f;
  x[idx] = v;
  xbf[idx] = f2bf(v);
}

// ---------------- bf16 MFMA GEMM, m97 structure ----------------
template<bool GATHER, bool BIAS, bool OBF16>
__global__ __launch_bounds__(256) void gemm_k(
    const unsigned short* __restrict__ A, long long lda, long long a_z,
    const unsigned short* __restrict__ B, long long ldb, long long b_z,
    const float* __restrict__ bias,
    void* __restrict__ C, long long ldc, long long c_z,
    int M, int N, int Kd, float scale,
    const int* __restrict__ glist, long long gl_z,
    const int* __restrict__ cnt, int mT, int nT, int Z)
{
  // bijective XCD-chunked swizzle (m204)
  int nwg = gridDim.x, bid = blockIdx.x;
  int q = nwg >> 3, r = nwg & 7;
  int xcd = bid & 7, j = bid >> 3;
  int wid = (xcd < r ? xcd * (q + 1) : r * (q + 1) + (xcd - r) * q) + j;
  // z fastest (balance), m middle, n outer (B-panel reuse per chunk)
  int z = wid % Z; int rem = wid / Z;
  int mt = rem % mT, nt = rem / mT;

  int Mz = cnt ? cnt[z] : M;
  int m0 = mt * 128, n0 = nt * 128;
  if (m0 >= Mz) return;

  const unsigned short* Ab = A + (size_t)z * a_z;
  const unsigned short* Bb = B + (size_t)z * b_z;

  __shared__ __align__(16) unsigned short As[128 * 64];
  __shared__ __align__(16) unsigned short Bs[128 * 64];

  int t = threadIdx.x, w = t >> 6, lane = t & 63;
  int wm = (w >> 1) * 64, wn = (w & 1) * 64;
  int fr = lane & 15, ksg = lane >> 4;
  int lrow = lane >> 3;
  int lchunk = ((lane & 7) ^ lrow) * 8;

  const unsigned short* ap[4];
  const unsigned short* bp[4];
  unsigned short* la[4];
  unsigned short* lb[4];
  #pragma unroll
  for (int i = 0; i < 4; ++i) {
    int rrow = w * 32 + i * 8 + lrow;
    int gr = m0 + rrow; if (gr >= Mz) gr = Mz - 1;
    int arow; if constexpr (GATHER) arow = glist[(size_t)z * gl_z + gr]; else arow = gr;
    ap[i] = Ab + (size_t)arow * lda + lchunk;
    int br = n0 + rrow; if (br >= N) br = N - 1;
    bp[i] = Bb + (size_t)br * ldb + lchunk;
    la[i] = &As[(w * 32 + i * 8) * 64];
    lb[i] = &Bs[(w * 32 + i * 8) * 64];
  }

  int rx = fr & 7;
  int off0 = ((0 + ksg) ^ rx) * 8;
  int off1 = ((4 + ksg) ^ rx) * 8;

  f32x4 acc[4][4] = {};

  for (int k0 = 0; k0 < Kd; k0 += 64) {
    #pragma unroll
    for (int i = 0; i < 4; ++i) GLD16(la[i], ap[i] + k0);
    #pragma unroll
    for (int i = 0; i < 4; ++i) GLD16(lb[i], bp[i] + k0);
    __syncthreads();
    #pragma unroll
    for (int kb = 0; kb < 2; ++kb) {
      int offk = kb ? off1 : off0;
      bf16x8 af[4], bv[4];
      #pragma unroll
      for (int m = 0; m < 4; ++m)
        af[m] = *(const bf16x8*)&As[(wm + m * 16 + fr) * 64 + offk];
      #pragma unroll
      for (int n = 0; n < 4; ++n)
        bv[n] = *(const bf16x8*)&Bs[(wn + n * 16 + fr) * 64 + offk];
      #pragma unroll
      for (int m = 0; m < 4; ++m)
        #pragma unroll
        for (int n = 0; n < 4; ++n)
          acc[m][n] = __builtin_amdgcn_mfma_f32_16x16x32_bf16(
              af[m], bv[n], acc[m][n], 0, 0, 0);
    }
    __syncthreads();
  }

  int rb = ksg * 4;
  #pragma unroll
  for (int m = 0; m < 4; ++m) {
    #pragma unroll
    for (int n = 0; n < 4; ++n) {
      int col = n0 + wn + n * 16 + fr;
      if (col >= N) continue;
      #pragma unroll
      for (int rr = 0; rr < 4; ++rr) {
        int row = m0 + wm + m * 16 + rb + rr;
        if (row >= Mz) continue;
        float v = acc[m][n][rr] * scale;
        if constexpr (BIAS) v += bias[col];
        size_t off = (size_t)z * c_z + (size_t)row * ldc + col;
        if constexpr (OBF16) ((unsigned short*)C)[off] = f2bf(v);
        else                 ((float*)C)[off] = v;
      }
    }
  }
}

// ---------------- V transpose: vt[h][d][k] = qkv[k][2D + h*64 + d] ----------------
__global__ __launch_bounds__(256) void transpose_v_k(
    const unsigned short* __restrict__ qkv, unsigned short* __restrict__ vt) {
  int kt = blockIdx.x;   // 0..31
  int h  = blockIdx.y;   // 0..11
  __shared__ unsigned short tile[64][72];
  int t = threadIdx.x;
  int r = t >> 2;             // 0..63
  int c0 = (t & 3) * 16;      // 0,16,32,48
  const unsigned short* src =
      qkv + (size_t)(kt * 64 + r) * (3 * DM) + 2 * DM + h * DHD + c0;
  *(int4*)&tile[r][c0]     = *(const int4*)(src);
  *(int4*)&tile[r][c0 + 8] = *(const int4*)(src + 8);
  __syncthreads();
  unsigned u[8];
  #pragma unroll
  for (int j = 0; j < 8; ++j)
    u[j] = (unsigned)tile[c0 + 2 * j][r] | ((unsigned)tile[c0 + 2 * j + 1][r] << 16);
  unsigned short* dst = vt + (size_t)(h * DHD + r) * SQ + kt * 64 + c0;
  *(int4*)dst       = make_int4((int)u[0], (int)u[1], (int)u[2], (int)u[3]);
  *(int4*)(dst + 8) = make_int4((int)u[4], (int)u[5], (int)u[6], (int)u[7]);
}

// ---------------- flash attention ----------------
// grid = NHD*32 blocks (h outer, qtile of 64 rows), 256 threads = 4 waves,
// wave w owns q-rows [w*16, w*16+16). K-tile 128 keys; online softmax.
__global__ __launch_bounds__(256) void flash_k(
    const unsigned short* __restrict__ qkv,   // [SQ][3*DM] bf16
    const unsigned short* __restrict__ vt,    // [NHD*DHD][SQ] bf16 (V^T)
    unsigned short* __restrict__ o)           // [SQ][DM] bf16
{
  int nwg = gridDim.x, bid = blockIdx.x;      // nwg = 384 (div by 8)
  int cpx = nwg >> 3;
  int wid = (bid & 7) * cpx + (bid >> 3);
  int h  = wid >> 5;
  int qt = wid & 31;
  int q0 = qt * 64;

  __shared__ __align__(16) unsigned short Ks[128 * 64];
  __shared__ __align__(16) unsigned short Vs[128 * 64];
  __shared__ __align__(16) unsigned short Ps[4][16 * 136];

  int t = threadIdx.x, w = t >> 6, lane = t & 63;
  int fr = lane & 15, ksg = lane >> 4;
  int lrow = lane >> 3;
  int lchunk = ((lane & 7) ^ lrow) * 8;

  // ---- stage Q (64x64) into Ks, then pull A-frags to regs ----
  const unsigned short* qbase = qkv + (size_t)q0 * (3 * DM) + h * DHD;
  #pragma unroll
  for (int i = 0; i < 2; ++i) {
    int rrow = w * 16 + i * 8 + lrow;
    GLD16(&Ks[(w * 16 + i * 8) * 64], qbase + (size_t)rrow * (3 * DM) + lchunk);
  }
  __syncthreads();
  bf16x8 qf[2];
  {
    int row = w * 16 + fr, ph = fr & 7;
    qf[0] = *(const bf16x8*)&Ks[row * 64 + ((ksg ^ ph) * 8)];
    qf[1] = *(const bf16x8*)&Ks[row * 64 + (((4 + ksg) ^ ph) * 8)];
  }
  __syncthreads();

  const unsigned short* kbase = qkv + DM + h * DHD;
  const unsigned short* vb = vt + (size_t)(h * DHD) * SQ;

  f32x4 oacc[4] = {};
  float m_r[4] = {-1e30f, -1e30f, -1e30f, -1e30f};
  float l_r[4] = {0.f, 0.f, 0.f, 0.f};

  for (int kt = 0; kt < SQ / 128; ++kt) {
    int kk0 = kt * 128;
    // stage K tile (128 keys x 64 dims)
    #pragma unroll
    for (int i = 0; i < 4; ++i) {
      int rrow = w * 32 + i * 8 + lrow;
      GLD16(&Ks[(w * 32 + i * 8) * 64],
            kbase + (size_t)(kk0 + rrow) * (3 * DM) + lchunk);
    }
    // stage V^T tile as 128 pseudo-rows p=d*2+half of 64 elems
    #pragma unroll
    for (int i = 0; i < 4; ++i) {
      int p = w * 32 + i * 8 + lrow;
      GLD16(&Vs[(w * 32 + i * 8) * 64],
            vb + (size_t)(p >> 1) * SQ + kk0 + (p & 1) * 64 + lchunk);
    }
    __syncthreads();

    // S = Q K^T : 1 m-frag x 8 n-frags, k=64 (2 steps)
    f32x4 sacc[8] = {};
    #pragma unroll
    for (int kb = 0; kb < 2; ++kb) {
      #pragma unroll
      for (int n = 0; n < 8; ++n) {
        int row = n * 16 + fr;
        bf16x8 bvv = *(const bf16x8*)&Ks[row * 64 +
            (((kb * 4 + ksg) ^ (fr & 7)) * 8)];
        sacc[n] = __builtin_amdgcn_mfma_f32_16x16x32_bf16(
            qf[kb], bvv, sacc[n], 0, 0, 0);
      }
    }

    // online softmax (rows = ksg*4 + r), scale 0.125 folded here
    #pragma unroll
    for (int r = 0; r < 4; ++r) {
      float mx = sacc[0][r];
      #pragma unroll
      for (int n = 1; n < 8; ++n) mx = fmaxf(mx, sacc[n][r]);
      mx = fmaxf(mx, __shfl_xor(mx, 1));
      mx = fmaxf(mx, __shfl_xor(mx, 2));
      mx = fmaxf(mx, __shfl_xor(mx, 4));
      mx = fmaxf(mx, __shfl_xor(mx, 8));
      float mn = fmaxf(m_r[r], mx * 0.125f);
      float resc = __expf(m_r[r] - mn);
      m_r[r] = mn;
      #pragma unroll
      for (int n = 0; n < 4; ++n) oacc[n][r] *= resc;
      float rs = 0.f;
      #pragma unroll
      for (int n = 0; n < 8; ++n) {
        float p = __expf(sacc[n][r] * 0.125f - mn);
        rs += p;
        Ps[w][(ksg * 4 + r) * 136 + n * 16 + fr] = f2bf(p);
      }
      rs += __shfl_xor(rs, 1);
      rs += __shfl_xor(rs, 2);
      rs += __shfl_xor(rs, 4);
      rs += __shfl_xor(rs, 8);
      l_r[r] = l_r[r] * resc + rs;
    }

    // PV: O += P (16x128) * V (128x64); A from own wave's Ps strip
    #pragma unroll
    for (int ksi = 0; ksi < 4; ++ksi) {
      bf16x8 pa = *(const bf16x8*)&Ps[w][fr * 136 + ksi * 32 + ksg * 8];
      #pragma unroll
      for (int n = 0; n < 4; ++n) {
        int p = (n * 16 + fr) * 2 + (ksi >> 1);
        int c = (ksi & 1) * 4 + ksg;
        bf16x8 bvv = *(const bf16x8*)&Vs[p * 64 + ((c ^ (p & 7)) * 8)];
        oacc[n] = __builtin_amdgcn_mfma_f32_16x16x32_bf16(
            pa, bvv, oacc[n], 0, 0, 0);
      }
    }
    __syncthreads();
  }

  // normalize + write o[q][h*64+d]
  unsigned short* ob = o + (size_t)(q0 + w * 16) * DM + h * DHD;
  #pragma unroll
  for (int r = 0; r < 4; ++r) {
    float invl = 1.f / l_r[r];
    int qrow = ksg * 4 + r;
    #pragma unroll
    for (int n = 0; n < 4; ++n)
      ob[(size_t)qrow * DM + n * 16 + fr] = f2bf(oacc[n][r] * invl);
  }
}

// ---------------- x = LN(x + add) ----------------
__global__ __launch_bounds__(256) void add_ln_k(const float* __restrict__ xin,
    const float* __restrict__ add, const float* __restrict__ w,
    const float* __restrict__ b, float* __restrict__ xout,
    unsigned short* __restrict__ xbf) {
  int row = blockIdx.x, t = threadIdx.x;
  const float* xi = xin + (size_t)row * DM;
  const float* ai = add + (size_t)row * DM;
  float v[3]; float s = 0.f, sq = 0.f;
  #pragma unroll
  for (int i = 0; i < 3; ++i) {
    int idx = t + i * 256;
    v[i] = xi[idx] + ai[idx];
    s += v[i]; sq += v[i] * v[i];
  }
  #pragma unroll
  for (int o = 32; o; o >>= 1) { s += __shfl_xor(s, o); sq += __shfl_xor(sq, o); }
  __shared__ float rsm[4], rqm[4];
  int wv = t >> 6;
  if ((t & 63) == 0) { rsm[wv] = s; rqm[wv] = sq; }
  __syncthreads();
  s = rsm[0] + rsm[1] + rsm[2] + rsm[3];
  sq = rqm[0] + rqm[1] + rqm[2] + rqm[3];
  float mean = s * (1.f / 768.f);
  float var = sq * (1.f / 768.f) - mean * mean;
  float inv = rsqrtf(var + 1e-5f);
  float* xo = xout + (size_t)row * DM;
  unsigned short* xb = xbf + (size_t)row * DM;
  #pragma unroll
  for (int i = 0; i < 3; ++i) {
    int idx = t + i * 256;
    float y = (v[i] - mean) * inv * w[idx] + b[idx];
    xo[idx] = y; xb[idx] = f2bf(y);
  }
}

// ---------------- gate: 8 dots, top-2, softmax, expert bucket lists ----------------
__global__ void gate_topk_k(const float* __restrict__ x, const float* __restrict__ gw,
    float* __restrict__ tw, int* __restrict__ ti, int* __restrict__ cnt,
    int* __restrict__ lists, int* __restrict__ slot) {
  int sIdx = blockIdx.x, lane = threadIdx.x;  // 64 threads
  const float* xr = x + (size_t)sIdx * DM;
  float acc[NE] = {};
  for (int d = lane; d < DM; d += 64) {
    float xv = xr[d];
    #pragma unroll
    for (int e = 0; e < NE; ++e) acc[e] += xv * gw[e * DM + d];
  }
  #pragma unroll
  for (int e = 0; e < NE; ++e) {
    #pragma unroll
    for (int o = 32; o; o >>= 1) acc[e] += __shfl_down(acc[e], o);
  }
  if (lane == 0) {
    float v0 = -1e30f, v1 = -1e30f; int i0 = 0, i1 = 0;
    #pragma unroll
    for (int e = 0; e < NE; ++e) {
      float v = acc[e];
      if (v > v0) { v1 = v0; i1 = i0; v0 = v; i0 = e; }
      else if (v > v1) { v1 = v; i1 = e; }
    }
    float e1 = expf(v1 - v0);
    float inv = 1.f / (1.f + e1);
    tw[sIdx * 2] = inv; tw[sIdx * 2 + 1] = e1 * inv;
    ti[sIdx * 2] = i0;  ti[sIdx * 2 + 1] = i1;
    int p0 = atomicAdd(&cnt[i0], 1); lists[i0 * SQ + p0] = sIdx; slot[sIdx * 2] = p0;
    int p1 = atomicAdd(&cnt[i1], 1); lists[i1 * SQ + p1] = sIdx; slot[sIdx * 2 + 1] = p1;
  }
}

__global__ void zero_k(int* __restrict__ c) {
  if (threadIdx.x < NE) c[threadIdx.x] = 0;
}

// ---------------- hh = silu(hg) * hu (in-place into hg) ----------------
__global__ __launch_bounds__(256) void silu_mul_k(unsigned short* __restrict__ hg,
    const unsigned short* __restrict__ hu, const int* __restrict__ cnt) {
  int e = blockIdx.y, sl = blockIdx.x;
  if (sl >= cnt[e]) return;
  size_t base = ((size_t)e * SQ + sl) * FF;
  int t = threadIdx.x;
  #pragma unroll
  for (int i = 0; i < FF / 256; ++i) {
    size_t idx = base + t + i * 256;
    float g = bf2f(hg[idx]);
    float u = bf2f(hu[idx]);
    float sv = g / (1.f + expf(-g));
    hg[idx] = f2bf(sv * u);
  }
}

// ---------------- moe combine + LN ----------------
__global__ __launch_bounds__(256) void combine_ln_k(const float* __restrict__ xin,
    const float* __restrict__ ye, const float* __restrict__ tw,
    const int* __restrict__ ti, const int* __restrict__ slot,
    const float* __restrict__ w, const float* __restrict__ b,
    float* __restrict__ xout, unsigned short* __restrict__ xbf) {
  int row = blockIdx.x, t = threadIdx.x;
  int e0 = ti[row * 2], e1 = ti[row * 2 + 1];
  int p0 = slot[row * 2], p1 = slot[row * 2 + 1];
  float w0 = tw[row * 2], w1 = tw[row * 2 + 1];
  const float* y0 = ye + ((size_t)e0 * SQ + p0) * DM;
  const float* y1 = ye + ((size_t)e1 * SQ + p1) * DM;
  const float* xi = xin + (size_t)row * DM;
  float v[3]; float s = 0.f, sq = 0.f;
  #pragma unroll
  for (int i = 0; i < 3; ++i) {
    int idx = t + i * 256;
    v[i] = xi[idx] + w0 * y0[idx] + w1 * y1[idx];
    s += v[i]; sq += v[i] * v[i];
  }
  #pragma unroll
  for (int o = 32; o; o >>= 1) { s += __shfl_xor(s, o); sq += __shfl_xor(sq, o); }
  __shared__ float rsm[4], rqm[4];
  int wv = t >> 6;
  if ((t & 63) == 0) { rsm[wv] = s; rqm[wv] = sq; }
  __syncthreads();
  s = rsm[0] + rsm[1] + rsm[2] + rsm[3];
  sq = rqm[0] + rqm[1] + rqm[2] + rqm[3];
  float mean = s * (1.f / 768.f);
  float var = sq * (1.f / 768.f) - mean * mean;
  float inv = rsqrtf(var + 1e-5f);
  float* xo = xout + (size_t)row * DM;
  unsigned short* xb = xbf + (size_t)row * DM;
  #pragma unroll
  for (int i = 0; i < 3; ++i) {
    int idx = t + i * 256;
    float y = (v[i] - mean) * inv * w[idx] + b[idx];
    xo[idx] = y; xb[idx] = f2bf(y);
  }
}

// ---------------- final RMSNorm -> bf16 ----------------
__global__ __launch_bounds__(256) void rms_k(const float* __restrict__ x,
    const float* __restrict__ rw, unsigned short* __restrict__ xbf) {
  int row = blockIdx.x, t = threadIdx.x;
  const float* xi = x + (size_t)row * DM;
  float v[3]; float sq = 0.f;
  #pragma unroll
  for (int i = 0; i < 3; ++i) {
    int idx = t + i * 256;
    v[i] = xi[idx];
    sq += v[i] * v[i];
  }
  #pragma unroll
  for (int o = 32; o; o >>= 1) sq += __shfl_xor(sq, o);
  __shared__ float rqm[4];
  int wv = t >> 6;
  if ((t & 63) == 0) rqm[wv] = sq;
  __syncthreads();
  sq = rqm[0] + rqm[1] + rqm[2] + rqm[3];
  float inv = rsqrtf(sq * (1.f / 768.f) + 1.1920929e-07f);
  unsigned short* xb = xbf + (size_t)row * DM;
  #pragma unroll
  for (int i = 0; i < 3; ++i) {
    int idx = t + i * 256;
    xb[idx] = f2bf(v[i] * inv * rw[idx]);
  }
}

// ================= host =================
extern "C" void kernel_launch(void* const* d_in, const int* in_sizes, int n_in,
                              void* d_out, int out_size, void* d_ws, size_t ws_size,
                              hipStream_t stream) {
  (void)in_sizes; (void)n_in; (void)out_size; (void)ws_size;
  const int*   tokens = (const int*)d_in[0];
  const float* emb    = (const float*)d_in[1];
  const float* qkv_w  = (const float*)d_in[2];
  const float* qkv_b  = (const float*)d_in[3];
  const float* out_w  = (const float*)d_in[4];
  const float* out_b  = (const float*)d_in[5];
  const float* ln1_w  = (const float*)d_in[6];
  const float* ln1_b  = (const float*)d_in[7];
  const float* ln2_w  = (const float*)d_in[8];
  const float* ln2_b  = (const float*)d_in[9];
  const float* gate_w = (const float*)d_in[10];
  const float* eg_w   = (const float*)d_in[11];
  const float* eu_w   = (const float*)d_in[12];
  const float* ed_w   = (const float*)d_in[13];
  const float* rms_w  = (const float*)d_in[14];
  float* out = (float*)d_out;

  char* wsb = (char*)d_ws;
  float*          x_f    = (float*)(wsb + 0);                   // 6291456
  unsigned short* x_bf   = (unsigned short*)(wsb + 6291456);    // 3145728
  unsigned short* qkv_bf = (unsigned short*)(wsb + 9437184);    // 9437184
  unsigned short* vt     = (unsigned short*)(wsb + 18874368);   // 3145728
  unsigned short* o_bf   = (unsigned short*)(wsb + 22020096);   // 3145728
  float*          tmp_f  = (float*)(wsb + 25165824);            // 6291456
  float*          tw     = (float*)(wsb + 31457280);            // 16384
  int*            ti     = (int*)(wsb + 31473664);              // 16384
  int*            cnt    = (int*)(wsb + 31490048);              // 256
  int*            lists  = (int*)(wsb + 31490304);              // 65536
  int*            slot   = (int*)(wsb + 31555840);              // 16384
  unsigned short* emb_bf = (unsigned short*)(wsb + 31572224);   // 49152000
  unsigned short* wbf    = (unsigned short*)(wsb + 80724224);   // 61341696
  unsigned short* hg     = (unsigned short*)(wsb + 142065920);
  unsigned short* hu     = (unsigned short*)(wsb + 142065920 + 50331648);
  float*          ye     = (float*)(wsb + 142065920 + 50331648); // overlaps hu (dead)

  unsigned short* qw_bf = wbf;                 // 1769472
  unsigned short* ow_bf = wbf + 1769472;       // 589824
  unsigned short* eg_bf = wbf + 2359296;       // 9437184
  unsigned short* eu_bf = wbf + 11796480;      // 9437184
  unsigned short* ed_bf = wbf + 21233664;      // 9437184

  conv_k<<<12000, 256, 0, stream>>>(emb, emb_bf);
  embed_k<<<SQ * DM / 256, 256, 0, stream>>>(tokens, emb, x_f, x_bf);

  for (int l = 0; l < NL; ++l) {
    const float* qw = qkv_w + (size_t)l * 3 * DM * DM;
    const float* qb = qkv_b + (size_t)l * 3 * DM;
    const float* ow = out_w + (size_t)l * DM * DM;
    const float* ob = out_b + (size_t)l * DM;
    const float* gw = gate_w + (size_t)l * NE * DM;
    const float* egw = eg_w + (size_t)l * NE * FF * DM;
    const float* euw = eu_w + (size_t)l * NE * FF * DM;
    const float* edw = ed_w + (size_t)l * NE * DM * FF;

    conv_k<<<864, 256, 0, stream>>>(qw, qw_bf);
    conv_k<<<288, 256, 0, stream>>>(ow, ow_bf);
    conv_k<<<4608, 256, 0, stream>>>(egw, eg_bf);
    conv_k<<<4608, 256, 0, stream>>>(euw, eu_bf);
    conv_k<<<4608, 256, 0, stream>>>(edw, ed_bf);

    // qkv = x @ qkv_w^T + b  -> bf16
    gemm_k<false, true, true><<<16 * 18, 256, 0, stream>>>(
        x_bf, DM, 0, qw_bf, DM, 0, qb, qkv_bf, 3 * DM, 0,
        SQ, 3 * DM, DM, 1.f, nullptr, 0, nullptr, 16, 18, 1);

    transpose_v_k<<<dim3(SQ / 64, NHD), 256, 0, stream>>>(qkv_bf, vt);

    // fused flash attention -> o_bf
    flash_k<<<NHD * 32, 256, 0, stream>>>(qkv_bf, vt, o_bf);

    // attn out-proj -> tmp_f (fp32)
    gemm_k<false, true, false><<<16 * 6, 256, 0, stream>>>(
        o_bf, DM, 0, ow_bf, DM, 0, ob, tmp_f, DM, 0,
        SQ, DM, DM, 1.f, nullptr, 0, nullptr, 16, 6, 1);

    add_ln_k<<<SQ, 256, 0, stream>>>(x_f, tmp_f, ln1_w + l * DM, ln1_b + l * DM,
                                     x_f, x_bf);

    zero_k<<<1, 64, 0, stream>>>(cnt);
    gate_topk_k<<<SQ, 64, 0, stream>>>(x_f, gw, tw, ti, cnt, lists, slot);

    gemm_k<true, false, true><<<16 * 12 * NE, 256, 0, stream>>>(
        x_bf, DM, 0, eg_bf, DM, (long long)FF * DM, nullptr,
        hg, FF, (long long)SQ * FF,
        SQ, FF, DM, 1.f, lists, SQ, cnt, 16, 12, NE);
    gemm_k<true, false, true><<<16 * 12 * NE, 256, 0, stream>>>(
        x_bf, DM, 0, eu_bf, DM, (long long)FF * DM, nullptr,
        hu, FF, (long long)SQ * FF,
        SQ, FF, DM, 1.f, lists, SQ, cnt, 16, 12, NE);

    silu_mul_k<<<dim3(SQ, NE), 256, 0, stream>>>(hg, hu, cnt);

    gemm_k<false, false, false><<<16 * 6 * NE, 256, 0, stream>>>(
        hg, FF, (long long)SQ * FF, ed_bf, FF, (long long)DM * FF, nullptr,
        ye, DM, (long long)SQ * DM,
        SQ, DM, FF, 1.f, nullptr, 0, cnt, 16, 6, NE);

    combine_ln_k<<<SQ, 256, 0, stream>>>(x_f, ye, tw, ti, slot,
                                         ln2_w + l * DM, ln2_b + l * DM,
                                         x_f, x_bf);
  }

  rms_k<<<SQ, 256, 0, stream>>>(x_f, rms_w, x_bf);

  // logits = xn @ emb_bf^T (fp32 out)
  gemm_k<false, false, false><<<16 * 250, 256, 0, stream>>>(
      x_bf, DM, 0, emb_bf, DM, 0, nullptr, out, NV, 0,
      SQ, NV, DM, 1.f, nullptr, 0, nullptr, 16, 250, 1);
}

// Round 5
// 834.251 us; speedup vs baseline: 1.3648x; 1.0159x over previous
//
#include <hip/hip_runtime.h>

// ---- problem dims ----
#define SQ   2048
#define DM   768
#define NHD  12
#define DHD  64
#define FF   1536
#define NE   8
#define NL   2
#define NV   32000

typedef __attribute__((ext_vector_type(8))) short bf16x8;
typedef __attribute__((ext_vector_type(4))) float f32x4;

__device__ __forceinline__ unsigned short f2bf(float f) {
  unsigned u = __float_as_uint(f);
  return (unsigned short)((u + 0x7fffu + ((u >> 16) & 1u)) >> 16);
}
__device__ __forceinline__ float bf2f(unsigned short h) {
  return __uint_as_float(((unsigned)h) << 16);
}

// async global->LDS, 16B per lane; dest = wave-uniform base + lane*16
#define GLD16(ldsp, gp) __builtin_amdgcn_global_load_lds( \
    (const __attribute__((address_space(1))) void*)(gp),  \
    (__attribute__((address_space(3))) void*)(ldsp), 16, 0, 0)

// ---------------- fp32 -> bf16 bulk convert (n must be /8, grid = n/8/256) ----
__global__ __launch_bounds__(256) void conv_k(const float* __restrict__ s,
    unsigned short* __restrict__ d) {
  size_t i = (size_t)(blockIdx.x * 256 + threadIdx.x) * 8;
  float4 a = *(const float4*)(s + i);
  float4 b = *(const float4*)(s + i + 4);
  int4 pk = make_int4(
      (int)((unsigned)f2bf(a.x) | ((unsigned)f2bf(a.y) << 16)),
      (int)((unsigned)f2bf(a.z) | ((unsigned)f2bf(a.w) << 16)),
      (int)((unsigned)f2bf(b.x) | ((unsigned)f2bf(b.y) << 16)),
      (int)((unsigned)f2bf(b.z) | ((unsigned)f2bf(b.w) << 16)));
  *(int4*)(d + i) = pk;
}

// ---------------- embedding: x = emb[tok]*sqrt(D) ----------------
__global__ __launch_bounds__(256) void embed_k(const int* __restrict__ tok,
    const float* __restrict__ emb, float* __restrict__ x,
    unsigned short* __restrict__ xbf) {
  int idx = blockIdx.x * 256 + threadIdx.x;   // < 2048*768
  int s = idx / DM, d = idx % DM;
  float v = emb[(size_t)tok[s] * DM + d] * 27.712812921102035f;
  x[idx] = v;
  xbf[idx] = f2bf(v);
}

// ================= pipelined 128x256 GEMM (logits engine) =================
// BM=128, BN=256, BK=64, 512 thr = 8 waves (2M x 4N), per-wave 64x64.
// Tri-buffered LDS (144 KB), prefetch depth 2 K-tiles, counted vmcnt(6),
// raw s_barrier (no drain), setprio around MFMA. Exact tiles only:
// M % 128 == 0, N % 256 == 0, K % 64 == 0, K/64 >= 3. fp32 C, no bias.
__global__ __launch_bounds__(512) void gemm256_k(
    const unsigned short* __restrict__ A, long long lda,
    const unsigned short* __restrict__ B, long long ldb,
    float* __restrict__ C, long long ldc,
    int Kd, int mT, int nT)
{
  int nwg = gridDim.x, bid = blockIdx.x;
  int q = nwg >> 3, r = nwg & 7;
  int xcd = bid & 7, j = bid >> 3;
  int wid = (xcd < r ? xcd * (q + 1) : r * (q + 1) + (xcd - r) * q) + j;
  int mt = wid % mT, nt = wid / mT;
  int m0 = mt * 128, n0 = nt * 256;
  (void)nT;

  // 3 bufs x 6 halves (A0,A1,B0,B1,B2,B3) x (64 rows x 64 cols) bf16
  __shared__ __align__(16) unsigned short lds[3 * 6 * 4096];

  int t = threadIdx.x, w = t >> 6, lane = t & 63;
  int wm = (w >> 2) * 64, wn = (w & 3) * 64;
  int fr = lane & 15, ksg = lane >> 4;
  int lrow = lane >> 3;                 // 0..7
  int lchunk = ((lane & 7) ^ lrow) * 8; // pre-swizzled source chunk

  // staging source pointers (halves: 0,1 = A; 2..5 = B)
  const unsigned short* sp[6];
  sp[0] = A + (size_t)(m0 +       w * 8 + lrow) * lda + lchunk;
  sp[1] = A + (size_t)(m0 +  64 + w * 8 + lrow) * lda + lchunk;
  #pragma unroll
  for (int h = 0; h < 4; ++h)
    sp[2 + h] = B + (size_t)(n0 + h * 64 + w * 8 + lrow) * ldb + lchunk;

  int rdA = (w >> 2) * 4096;        // this wave's A half
  int rdB = (2 + (w & 3)) * 4096;   // this wave's B half
  int stDst = w * 512;              // wave dest offset within a half (elems)

  int rx = fr & 7;
  int off0 = (ksg ^ rx) * 8;
  int off1 = ((4 + ksg) ^ rx) * 8;

  int KT = Kd >> 6;
  f32x4 acc[4][4] = {};

  // prologue: stage K-tiles 0 and 1
  #pragma unroll
  for (int h = 0; h < 6; ++h)
    GLD16(&lds[h * 4096 + stDst], sp[h]);
  #pragma unroll
  for (int h = 0; h < 6; ++h)
    GLD16(&lds[(6 + h) * 4096 + stDst], sp[h] + 64);
  asm volatile("s_waitcnt vmcnt(6)" ::: "memory");   // tile 0 landed
  __builtin_amdgcn_s_barrier();
  __builtin_amdgcn_sched_barrier(0);

  int buf = 0;
  for (int kt = 0; kt < KT; ++kt) {
    const unsigned short* Abl = &lds[buf * 6 * 4096 + rdA];
    const unsigned short* Bbl = &lds[buf * 6 * 4096 + rdB];
    int pf = (kt + 2 < KT);
    int pbuf = buf + 2; if (pbuf >= 3) pbuf -= 3;
    unsigned short* pd = &lds[pbuf * 6 * 4096 + stDst];
    long long koff = (long long)(kt + 2) * 64;

    if (pf) {
      GLD16(pd + 0 * 4096, sp[0] + koff);
      GLD16(pd + 1 * 4096, sp[1] + koff);
      GLD16(pd + 2 * 4096, sp[2] + koff);
    }
    {
      bf16x8 af[4], bv[4];
      #pragma unroll
      for (int m = 0; m < 4; ++m)
        af[m] = *(const bf16x8*)&Abl[(m * 16 + fr) * 64 + off0];
      #pragma unroll
      for (int n = 0; n < 4; ++n)
        bv[n] = *(const bf16x8*)&Bbl[(n * 16 + fr) * 64 + off0];
      __builtin_amdgcn_s_setprio(1);
      #pragma unroll
      for (int m = 0; m < 4; ++m)
        #pragma unroll
        for (int n = 0; n < 4; ++n)
          acc[m][n] = __builtin_amdgcn_mfma_f32_16x16x32_bf16(
              af[m], bv[n], acc[m][n], 0, 0, 0);
      __builtin_amdgcn_s_setprio(0);
    }
    if (pf) {
      GLD16(pd + 3 * 4096, sp[3] + koff);
      GLD16(pd + 4 * 4096, sp[4] + koff);
      GLD16(pd + 5 * 4096, sp[5] + koff);
    }
    {
      bf16x8 af[4], bv[4];
      #pragma unroll
      for (int m = 0; m < 4; ++m)
        af[m] = *(const bf16x8*)&Abl[(m * 16 + fr) * 64 + off1];
      #pragma unroll
      for (int n = 0; n < 4; ++n)
        bv[n] = *(const bf16x8*)&Bbl[(n * 16 + fr) * 64 + off1];
      __builtin_amdgcn_s_setprio(1);
      #pragma unroll
      for (int m = 0; m < 4; ++m)
        #pragma unroll
        for (int n = 0; n < 4; ++n)
          acc[m][n] = __builtin_amdgcn_mfma_f32_16x16x32_bf16(
              af[m], bv[n], acc[m][n], 0, 0, 0);
      __builtin_amdgcn_s_setprio(0);
    }
    // boundary: ensure next tile fully resident; keep t+2's 6 loads in flight
    if (pf) {
      asm volatile("s_waitcnt vmcnt(6)" ::: "memory");
    } else if (kt + 1 < KT) {
      asm volatile("s_waitcnt vmcnt(0)" ::: "memory");
    }
    __builtin_amdgcn_s_barrier();
    __builtin_amdgcn_sched_barrier(0);
    buf = buf + 1; if (buf == 3) buf = 0;
  }

  // epilogue
  int rb = ksg * 4;
  #pragma unroll
  for (int m = 0; m < 4; ++m)
    #pragma unroll
    for (int n = 0; n < 4; ++n)
      #pragma unroll
      for (int rr = 0; rr < 4; ++rr)
        C[(size_t)(m0 + wm + m * 16 + rb + rr) * ldc + (n0 + wn + n * 16 + fr)] =
            acc[m][n][rr];
}

// ---------------- bf16 MFMA GEMM, m97 structure ----------------
template<bool GATHER, bool BIAS, bool OBF16>
__global__ __launch_bounds__(256) void gemm_k(
    const unsigned short* __restrict__ A, long long lda, long long a_z,
    const unsigned short* __restrict__ B, long long ldb, long long b_z,
    const float* __restrict__ bias,
    void* __restrict__ C, long long ldc, long long c_z,
    int M, int N, int Kd, float scale,
    const int* __restrict__ glist, long long gl_z,
    const int* __restrict__ cnt, int mT, int nT, int Z)
{
  // bijective XCD-chunked swizzle (m204)
  int nwg = gridDim.x, bid = blockIdx.x;
  int q = nwg >> 3, r = nwg & 7;
  int xcd = bid & 7, j = bid >> 3;
  int wid = (xcd < r ? xcd * (q + 1) : r * (q + 1) + (xcd - r) * q) + j;
  // z fastest (balance), m middle, n outer (B-panel reuse per chunk)
  int z = wid % Z; int rem = wid / Z;
  int mt = rem % mT, nt = rem / mT;

  int Mz = cnt ? cnt[z] : M;
  int m0 = mt * 128, n0 = nt * 128;
  if (m0 >= Mz) return;

  const unsigned short* Ab = A + (size_t)z * a_z;
  const unsigned short* Bb = B + (size_t)z * b_z;

  __shared__ __align__(16) unsigned short As[128 * 64];
  __shared__ __align__(16) unsigned short Bs[128 * 64];

  int t = threadIdx.x, w = t >> 6, lane = t & 63;
  int wm = (w >> 1) * 64, wn = (w & 1) * 64;
  int fr = lane & 15, ksg = lane >> 4;
  int lrow = lane >> 3;
  int lchunk = ((lane & 7) ^ lrow) * 8;

  const unsigned short* ap[4];
  const unsigned short* bp[4];
  unsigned short* la[4];
  unsigned short* lb[4];
  #pragma unroll
  for (int i = 0; i < 4; ++i) {
    int rrow = w * 32 + i * 8 + lrow;
    int gr = m0 + rrow; if (gr >= Mz) gr = Mz - 1;
    int arow; if constexpr (GATHER) arow = glist[(size_t)z * gl_z + gr]; else arow = gr;
    ap[i] = Ab + (size_t)arow * lda + lchunk;
    int br = n0 + rrow; if (br >= N) br = N - 1;
    bp[i] = Bb + (size_t)br * ldb + lchunk;
    la[i] = &As[(w * 32 + i * 8) * 64];
    lb[i] = &Bs[(w * 32 + i * 8) * 64];
  }

  int rx = fr & 7;
  int off0 = ((0 + ksg) ^ rx) * 8;
  int off1 = ((4 + ksg) ^ rx) * 8;

  f32x4 acc[4][4] = {};

  for (int k0 = 0; k0 < Kd; k0 += 64) {
    #pragma unroll
    for (int i = 0; i < 4; ++i) GLD16(la[i], ap[i] + k0);
    #pragma unroll
    for (int i = 0; i < 4; ++i) GLD16(lb[i], bp[i] + k0);
    __syncthreads();
    #pragma unroll
    for (int kb = 0; kb < 2; ++kb) {
      int offk = kb ? off1 : off0;
      bf16x8 af[4], bv[4];
      #pragma unroll
      for (int m = 0; m < 4; ++m)
        af[m] = *(const bf16x8*)&As[(wm + m * 16 + fr) * 64 + offk];
      #pragma unroll
      for (int n = 0; n < 4; ++n)
        bv[n] = *(const bf16x8*)&Bs[(wn + n * 16 + fr) * 64 + offk];
      #pragma unroll
      for (int m = 0; m < 4; ++m)
        #pragma unroll
        for (int n = 0; n < 4; ++n)
          acc[m][n] = __builtin_amdgcn_mfma_f32_16x16x32_bf16(
              af[m], bv[n], acc[m][n], 0, 0, 0);
    }
    __syncthreads();
  }

  int rb = ksg * 4;
  #pragma unroll
  for (int m = 0; m < 4; ++m) {
    #pragma unroll
    for (int n = 0; n < 4; ++n) {
      int col = n0 + wn + n * 16 + fr;
      if (col >= N) continue;
      #pragma unroll
      for (int rr = 0; rr < 4; ++rr) {
        int row = m0 + wm + m * 16 + rb + rr;
        if (row >= Mz) continue;
        float v = acc[m][n][rr] * scale;
        if constexpr (BIAS) v += bias[col];
        size_t off = (size_t)z * c_z + (size_t)row * ldc + col;
        if constexpr (OBF16) ((unsigned short*)C)[off] = f2bf(v);
        else                 ((float*)C)[off] = v;
      }
    }
  }
}

// ---------------- V transpose: vt[h][d][k] = qkv[k][2D + h*64 + d] ----------------
__global__ __launch_bounds__(256) void transpose_v_k(
    const unsigned short* __restrict__ qkv, unsigned short* __restrict__ vt) {
  int kt = blockIdx.x;   // 0..31
  int h  = blockIdx.y;   // 0..11
  __shared__ unsigned short tile[64][72];
  int t = threadIdx.x;
  int r = t >> 2;             // 0..63
  int c0 = (t & 3) * 16;      // 0,16,32,48
  const unsigned short* src =
      qkv + (size_t)(kt * 64 + r) * (3 * DM) + 2 * DM + h * DHD + c0;
  *(int4*)&tile[r][c0]     = *(const int4*)(src);
  *(int4*)&tile[r][c0 + 8] = *(const int4*)(src + 8);
  __syncthreads();
  unsigned u[8];
  #pragma unroll
  for (int j = 0; j < 8; ++j)
    u[j] = (unsigned)tile[c0 + 2 * j][r] | ((unsigned)tile[c0 + 2 * j + 1][r] << 16);
  unsigned short* dst = vt + (size_t)(h * DHD + r) * SQ + kt * 64 + c0;
  *(int4*)dst       = make_int4((int)u[0], (int)u[1], (int)u[2], (int)u[3]);
  *(int4*)(dst + 8) = make_int4((int)u[4], (int)u[5], (int)u[6], (int)u[7]);
}

// ---------------- flash attention ----------------
__global__ __launch_bounds__(256) void flash_k(
    const unsigned short* __restrict__ qkv,   // [SQ][3*DM] bf16
    const unsigned short* __restrict__ vt,    // [NHD*DHD][SQ] bf16 (V^T)
    unsigned short* __restrict__ o)           // [SQ][DM] bf16
{
  int nwg = gridDim.x, bid = blockIdx.x;      // nwg = 384 (div by 8)
  int cpx = nwg >> 3;
  int wid = (bid & 7) * cpx + (bid >> 3);
  int h  = wid >> 5;
  int qt = wid & 31;
  int q0 = qt * 64;

  __shared__ __align__(16) unsigned short Ks[128 * 64];
  __shared__ __align__(16) unsigned short Vs[128 * 64];
  __shared__ __align__(16) unsigned short Ps[4][16 * 136];

  int t = threadIdx.x, w = t >> 6, lane = t & 63;
  int fr = lane & 15, ksg = lane >> 4;
  int lrow = lane >> 3;
  int lchunk = ((lane & 7) ^ lrow) * 8;

  const unsigned short* qbase = qkv + (size_t)q0 * (3 * DM) + h * DHD;
  #pragma unroll
  for (int i = 0; i < 2; ++i) {
    int rrow = w * 16 + i * 8 + lrow;
    GLD16(&Ks[(w * 16 + i * 8) * 64], qbase + (size_t)rrow * (3 * DM) + lchunk);
  }
  __syncthreads();
  bf16x8 qf[2];
  {
    int row = w * 16 + fr, ph = fr & 7;
    qf[0] = *(const bf16x8*)&Ks[row * 64 + ((ksg ^ ph) * 8)];
    qf[1] = *(const bf16x8*)&Ks[row * 64 + (((4 + ksg) ^ ph) * 8)];
  }
  __syncthreads();

  const unsigned short* kbase = qkv + DM + h * DHD;
  const unsigned short* vb = vt + (size_t)(h * DHD) * SQ;

  f32x4 oacc[4] = {};
  float m_r[4] = {-1e30f, -1e30f, -1e30f, -1e30f};
  float l_r[4] = {0.f, 0.f, 0.f, 0.f};

  for (int kt = 0; kt < SQ / 128; ++kt) {
    int kk0 = kt * 128;
    #pragma unroll
    for (int i = 0; i < 4; ++i) {
      int rrow = w * 32 + i * 8 + lrow;
      GLD16(&Ks[(w * 32 + i * 8) * 64],
            kbase + (size_t)(kk0 + rrow) * (3 * DM) + lchunk);
    }
    #pragma unroll
    for (int i = 0; i < 4; ++i) {
      int p = w * 32 + i * 8 + lrow;
      GLD16(&Vs[(w * 32 + i * 8) * 64],
            vb + (size_t)(p >> 1) * SQ + kk0 + (p & 1) * 64 + lchunk);
    }
    __syncthreads();

    f32x4 sacc[8] = {};
    #pragma unroll
    for (int kb = 0; kb < 2; ++kb) {
      #pragma unroll
      for (int n = 0; n < 8; ++n) {
        int row = n * 16 + fr;
        bf16x8 bvv = *(const bf16x8*)&Ks[row * 64 +
            (((kb * 4 + ksg) ^ (fr & 7)) * 8)];
        sacc[n] = __builtin_amdgcn_mfma_f32_16x16x32_bf16(
            qf[kb], bvv, sacc[n], 0, 0, 0);
      }
    }

    #pragma unroll
    for (int r = 0; r < 4; ++r) {
      float mx = sacc[0][r];
      #pragma unroll
      for (int n = 1; n < 8; ++n) mx = fmaxf(mx, sacc[n][r]);
      mx = fmaxf(mx, __shfl_xor(mx, 1));
      mx = fmaxf(mx, __shfl_xor(mx, 2));
      mx = fmaxf(mx, __shfl_xor(mx, 4));
      mx = fmaxf(mx, __shfl_xor(mx, 8));
      float mn = fmaxf(m_r[r], mx * 0.125f);
      float resc = __expf(m_r[r] - mn);
      m_r[r] = mn;
      #pragma unroll
      for (int n = 0; n < 4; ++n) oacc[n][r] *= resc;
      float rs = 0.f;
      #pragma unroll
      for (int n = 0; n < 8; ++n) {
        float p = __expf(sacc[n][r] * 0.125f - mn);
        rs += p;
        Ps[w][(ksg * 4 + r) * 136 + n * 16 + fr] = f2bf(p);
      }
      rs += __shfl_xor(rs, 1);
      rs += __shfl_xor(rs, 2);
      rs += __shfl_xor(rs, 4);
      rs += __shfl_xor(rs, 8);
      l_r[r] = l_r[r] * resc + rs;
    }

    #pragma unroll
    for (int ksi = 0; ksi < 4; ++ksi) {
      bf16x8 pa = *(const bf16x8*)&Ps[w][fr * 136 + ksi * 32 + ksg * 8];
      #pragma unroll
      for (int n = 0; n < 4; ++n) {
        int p = (n * 16 + fr) * 2 + (ksi >> 1);
        int c = (ksi & 1) * 4 + ksg;
        bf16x8 bvv = *(const bf16x8*)&Vs[p * 64 + ((c ^ (p & 7)) * 8)];
        oacc[n] = __builtin_amdgcn_mfma_f32_16x16x32_bf16(
            pa, bvv, oacc[n], 0, 0, 0);
      }
    }
    __syncthreads();
  }

  unsigned short* ob = o + (size_t)(q0 + w * 16) * DM + h * DHD;
  #pragma unroll
  for (int r = 0; r < 4; ++r) {
    float invl = 1.f / l_r[r];
    int qrow = ksg * 4 + r;
    #pragma unroll
    for (int n = 0; n < 4; ++n)
      ob[(size_t)qrow * DM + n * 16 + fr] = f2bf(oacc[n][r] * invl);
  }
}

// ---------------- x = LN(x + add) ----------------
__global__ __launch_bounds__(256) void add_ln_k(const float* __restrict__ xin,
    const float* __restrict__ add, const float* __restrict__ w,
    const float* __restrict__ b, float* __restrict__ xout,
    unsigned short* __restrict__ xbf) {
  int row = blockIdx.x, t = threadIdx.x;
  const float* xi = xin + (size_t)row * DM;
  const float* ai = add + (size_t)row * DM;
  float v[3]; float s = 0.f, sq = 0.f;
  #pragma unroll
  for (int i = 0; i < 3; ++i) {
    int idx = t + i * 256;
    v[i] = xi[idx] + ai[idx];
    s += v[i]; sq += v[i] * v[i];
  }
  #pragma unroll
  for (int o = 32; o; o >>= 1) { s += __shfl_xor(s, o); sq += __shfl_xor(sq, o); }
  __shared__ float rsm[4], rqm[4];
  int wv = t >> 6;
  if ((t & 63) == 0) { rsm[wv] = s; rqm[wv] = sq; }
  __syncthreads();
  s = rsm[0] + rsm[1] + rsm[2] + rsm[3];
  sq = rqm[0] + rqm[1] + rqm[2] + rqm[3];
  float mean = s * (1.f / 768.f);
  float var = sq * (1.f / 768.f) - mean * mean;
  float inv = rsqrtf(var + 1e-5f);
  float* xo = xout + (size_t)row * DM;
  unsigned short* xb = xbf + (size_t)row * DM;
  #pragma unroll
  for (int i = 0; i < 3; ++i) {
    int idx = t + i * 256;
    float y = (v[i] - mean) * inv * w[idx] + b[idx];
    xo[idx] = y; xb[idx] = f2bf(y);
  }
}

// ---------------- gate: 8 dots, top-2, softmax, expert bucket lists ----------------
__global__ void gate_topk_k(const float* __restrict__ x, const float* __restrict__ gw,
    float* __restrict__ tw, int* __restrict__ ti, int* __restrict__ cnt,
    int* __restrict__ lists, int* __restrict__ slot) {
  int sIdx = blockIdx.x, lane = threadIdx.x;  // 64 threads
  const float* xr = x + (size_t)sIdx * DM;
  float acc[NE] = {};
  for (int d = lane; d < DM; d += 64) {
    float xv = xr[d];
    #pragma unroll
    for (int e = 0; e < NE; ++e) acc[e] += xv * gw[e * DM + d];
  }
  #pragma unroll
  for (int e = 0; e < NE; ++e) {
    #pragma unroll
    for (int o = 32; o; o >>= 1) acc[e] += __shfl_down(acc[e], o);
  }
  if (lane == 0) {
    float v0 = -1e30f, v1 = -1e30f; int i0 = 0, i1 = 0;
    #pragma unroll
    for (int e = 0; e < NE; ++e) {
      float v = acc[e];
      if (v > v0) { v1 = v0; i1 = i0; v0 = v; i0 = e; }
      else if (v > v1) { v1 = v; i1 = e; }
    }
    float e1 = expf(v1 - v0);
    float inv = 1.f / (1.f + e1);
    tw[sIdx * 2] = inv; tw[sIdx * 2 + 1] = e1 * inv;
    ti[sIdx * 2] = i0;  ti[sIdx * 2 + 1] = i1;
    int p0 = atomicAdd(&cnt[i0], 1); lists[i0 * SQ + p0] = sIdx; slot[sIdx * 2] = p0;
    int p1 = atomicAdd(&cnt[i1], 1); lists[i1 * SQ + p1] = sIdx; slot[sIdx * 2 + 1] = p1;
  }
}

__global__ void zero_k(int* __restrict__ c) {
  if (threadIdx.x < NE) c[threadIdx.x] = 0;
}

// ---------------- hh = silu(hg) * hu (in-place into hg) ----------------
__global__ __launch_bounds__(256) void silu_mul_k(unsigned short* __restrict__ hg,
    const unsigned short* __restrict__ hu, const int* __restrict__ cnt) {
  int e = blockIdx.y, sl = blockIdx.x;
  if (sl >= cnt[e]) return;
  size_t base = ((size_t)e * SQ + sl) * FF;
  int t = threadIdx.x;
  #pragma unroll
  for (int i = 0; i < FF / 256; ++i) {
    size_t idx = base + t + i * 256;
    float g = bf2f(hg[idx]);
    float u = bf2f(hu[idx]);
    float sv = g / (1.f + expf(-g));
    hg[idx] = f2bf(sv * u);
  }
}

// ---------------- moe combine + LN ----------------
__global__ __launch_bounds__(256) void combine_ln_k(const float* __restrict__ xin,
    const float* __restrict__ ye, const float* __restrict__ tw,
    const int* __restrict__ ti, const int* __restrict__ slot,
    const float* __restrict__ w, const float* __restrict__ b,
    float* __restrict__ xout, unsigned short* __restrict__ xbf) {
  int row = blockIdx.x, t = threadIdx.x;
  int e0 = ti[row * 2], e1 = ti[row * 2 + 1];
  int p0 = slot[row * 2], p1 = slot[row * 2 + 1];
  float w0 = tw[row * 2], w1 = tw[row * 2 + 1];
  const float* y0 = ye + ((size_t)e0 * SQ + p0) * DM;
  const float* y1 = ye + ((size_t)e1 * SQ + p1) * DM;
  const float* xi = xin + (size_t)row * DM;
  float v[3]; float s = 0.f, sq = 0.f;
  #pragma unroll
  for (int i = 0; i < 3; ++i) {
    int idx = t + i * 256;
    v[i] = xi[idx] + w0 * y0[idx] + w1 * y1[idx];
    s += v[i]; sq += v[i] * v[i];
  }
  #pragma unroll
  for (int o = 32; o; o >>= 1) { s += __shfl_xor(s, o); sq += __shfl_xor(sq, o); }
  __shared__ float rsm[4], rqm[4];
  int wv = t >> 6;
  if ((t & 63) == 0) { rsm[wv] = s; rqm[wv] = sq; }
  __syncthreads();
  s = rsm[0] + rsm[1] + rsm[2] + rsm[3];
  sq = rqm[0] + rqm[1] + rqm[2] + rqm[3];
  float mean = s * (1.f / 768.f);
  float var = sq * (1.f / 768.f) - mean * mean;
  float inv = rsqrtf(var + 1e-5f);
  float* xo = xout + (size_t)row * DM;
  unsigned short* xb = xbf + (size_t)row * DM;
  #pragma unroll
  for (int i = 0; i < 3; ++i) {
    int idx = t + i * 256;
    float y = (v[i] - mean) * inv * w[idx] + b[idx];
    xo[idx] = y; xb[idx] = f2bf(y);
  }
}

// ---------------- final RMSNorm -> bf16 ----------------
__global__ __launch_bounds__(256) void rms_k(const float* __restrict__ x,
    const float* __restrict__ rw, unsigned short* __restrict__ xbf) {
  int row = blockIdx.x, t = threadIdx.x;
  const float* xi = x + (size_t)row * DM;
  float v[3]; float sq = 0.f;
  #pragma unroll
  for (int i = 0; i < 3; ++i) {
    int idx = t + i * 256;
    v[i] = xi[idx];
    sq += v[i] * v[i];
  }
  #pragma unroll
  for (int o = 32; o; o >>= 1) sq += __shfl_xor(sq, o);
  __shared__ float rqm[4];
  int wv = t >> 6;
  if ((t & 63) == 0) rqm[wv] = sq;
  __syncthreads();
  sq = rqm[0] + rqm[1] + rqm[2] + rqm[3];
  float inv = rsqrtf(sq * (1.f / 768.f) + 1.1920929e-07f);
  unsigned short* xb = xbf + (size_t)row * DM;
  #pragma unroll
  for (int i = 0; i < 3; ++i) {
    int idx = t + i * 256;
    xb[idx] = f2bf(v[i] * inv * rw[idx]);
  }
}

// ================= host =================
extern "C" void kernel_launch(void* const* d_in, const int* in_sizes, int n_in,
                              void* d_out, int out_size, void* d_ws, size_t ws_size,
                              hipStream_t stream) {
  (void)in_sizes; (void)n_in; (void)out_size; (void)ws_size;
  const int*   tokens = (const int*)d_in[0];
  const float* emb    = (const float*)d_in[1];
  const float* qkv_w  = (const float*)d_in[2];
  const float* qkv_b  = (const float*)d_in[3];
  const float* out_w  = (const float*)d_in[4];
  const float* out_b  = (const float*)d_in[5];
  const float* ln1_w  = (const float*)d_in[6];
  const float* ln1_b  = (const float*)d_in[7];
  const float* ln2_w  = (const float*)d_in[8];
  const float* ln2_b  = (const float*)d_in[9];
  const float* gate_w = (const float*)d_in[10];
  const float* eg_w   = (const float*)d_in[11];
  const float* eu_w   = (const float*)d_in[12];
  const float* ed_w   = (const float*)d_in[13];
  const float* rms_w  = (const float*)d_in[14];
  float* out = (float*)d_out;

  char* wsb = (char*)d_ws;
  float*          x_f    = (float*)(wsb + 0);                   // 6291456
  unsigned short* x_bf   = (unsigned short*)(wsb + 6291456);    // 3145728
  unsigned short* qkv_bf = (unsigned short*)(wsb + 9437184);    // 9437184
  unsigned short* vt     = (unsigned short*)(wsb + 18874368);   // 3145728
  unsigned short* o_bf   = (unsigned short*)(wsb + 22020096);   // 3145728
  float*          tmp_f  = (float*)(wsb + 25165824);            // 6291456
  float*          tw     = (float*)(wsb + 31457280);            // 16384
  int*            ti     = (int*)(wsb + 31473664);              // 16384
  int*            cnt    = (int*)(wsb + 31490048);              // 256
  int*            lists  = (int*)(wsb + 31490304);              // 65536
  int*            slot   = (int*)(wsb + 31555840);              // 16384
  unsigned short* emb_bf = (unsigned short*)(wsb + 31572224);   // 49152000
  unsigned short* wbf    = (unsigned short*)(wsb + 80724224);   // 61341696
  unsigned short* hg     = (unsigned short*)(wsb + 142065920);
  unsigned short* hu     = (unsigned short*)(wsb + 142065920 + 50331648);
  float*          ye     = (float*)(wsb + 142065920 + 50331648); // overlaps hu (dead)

  unsigned short* qw_bf = wbf;                 // 1769472
  unsigned short* ow_bf = wbf + 1769472;       // 589824
  unsigned short* eg_bf = wbf + 2359296;       // 9437184
  unsigned short* eu_bf = wbf + 11796480;      // 9437184
  unsigned short* ed_bf = wbf + 21233664;      // 9437184

  conv_k<<<12000, 256, 0, stream>>>(emb, emb_bf);
  embed_k<<<SQ * DM / 256, 256, 0, stream>>>(tokens, emb, x_f, x_bf);

  for (int l = 0; l < NL; ++l) {
    const float* qw = qkv_w + (size_t)l * 3 * DM * DM;
    const float* qb = qkv_b + (size_t)l * 3 * DM;
    const float* ow = out_w + (size_t)l * DM * DM;
    const float* ob = out_b + (size_t)l * DM;
    const float* gw = gate_w + (size_t)l * NE * DM;
    const float* egw = eg_w + (size_t)l * NE * FF * DM;
    const float* euw = eu_w + (size_t)l * NE * FF * DM;
    const float* edw = ed_w + (size_t)l * NE * DM * FF;

    conv_k<<<864, 256, 0, stream>>>(qw, qw_bf);
    conv_k<<<288, 256, 0, stream>>>(ow, ow_bf);
    conv_k<<<4608, 256, 0, stream>>>(egw, eg_bf);
    conv_k<<<4608, 256, 0, stream>>>(euw, eu_bf);
    conv_k<<<4608, 256, 0, stream>>>(edw, ed_bf);

    // qkv = x @ qkv_w^T + b  -> bf16
    gemm_k<false, true, true><<<16 * 18, 256, 0, stream>>>(
        x_bf, DM, 0, qw_bf, DM, 0, qb, qkv_bf, 3 * DM, 0,
        SQ, 3 * DM, DM, 1.f, nullptr, 0, nullptr, 16, 18, 1);

    transpose_v_k<<<dim3(SQ / 64, NHD), 256, 0, stream>>>(qkv_bf, vt);

    // fused flash attention -> o_bf
    flash_k<<<NHD * 32, 256, 0, stream>>>(qkv_bf, vt, o_bf);

    // attn out-proj -> tmp_f (fp32)
    gemm_k<false, true, false><<<16 * 6, 256, 0, stream>>>(
        o_bf, DM, 0, ow_bf, DM, 0, ob, tmp_f, DM, 0,
        SQ, DM, DM, 1.f, nullptr, 0, nullptr, 16, 6, 1);

    add_ln_k<<<SQ, 256, 0, stream>>>(x_f, tmp_f, ln1_w + l * DM, ln1_b + l * DM,
                                     x_f, x_bf);

    zero_k<<<1, 64, 0, stream>>>(cnt);
    gate_topk_k<<<SQ, 64, 0, stream>>>(x_f, gw, tw, ti, cnt, lists, slot);

    gemm_k<true, false, true><<<16 * 12 * NE, 256, 0, stream>>>(
        x_bf, DM, 0, eg_bf, DM, (long long)FF * DM, nullptr,
        hg, FF, (long long)SQ * FF,
        SQ, FF, DM, 1.f, lists, SQ, cnt, 16, 12, NE);
    gemm_k<true, false, true><<<16 * 12 * NE, 256, 0, stream>>>(
        x_bf, DM, 0, eu_bf, DM, (long long)FF * DM, nullptr,
        hu, FF, (long long)SQ * FF,
        SQ, FF, DM, 1.f, lists, SQ, cnt, 16, 12, NE);

    silu_mul_k<<<dim3(SQ, NE), 256, 0, stream>>>(hg, hu, cnt);

    gemm_k<false, false, false><<<16 * 6 * NE, 256, 0, stream>>>(
        hg, FF, (long long)SQ * FF, ed_bf, FF, (long long)DM * FF, nullptr,
        ye, DM, (long long)SQ * DM,
        SQ, DM, FF, 1.f, nullptr, 0, cnt, 16, 6, NE);

    combine_ln_k<<<SQ, 256, 0, stream>>>(x_f, ye, tw, ti, slot,
                                         ln2_w + l * DM, ln2_b + l * DM,
                                         x_f, x_bf);
  }

  rms_k<<<SQ, 256, 0, stream>>>(x_f, rms_w, x_bf);

  // logits = xn @ emb_bf^T (fp32 out) -- pipelined engine
  // M=2048 (mT=16 x 128), N=32000 (nT=125 x 256), K=768 (12 K-tiles)
  gemm256_k<<<16 * 125, 512, 0, stream>>>(
      x_bf, DM, emb_bf, DM, out, NV, DM, 16, 125);
}

// Round 6
// 813.130 us; speedup vs baseline: 1.4003x; 1.0260x over previous
//
#include <hip/hip_runtime.h>

// ---- problem dims ----
#define SQ   2048
#define DM   768
#define NHD  12
#define DHD  64
#define FF   1536
#define NE   8
#define NL   2
#define NV   32000

typedef __attribute__((ext_vector_type(8))) short bf16x8;
typedef __attribute__((ext_vector_type(4))) float f32x4;

__device__ __forceinline__ unsigned short f2bf(float f) {
  unsigned u = __float_as_uint(f);
  return (unsigned short)((u + 0x7fffu + ((u >> 16) & 1u)) >> 16);
}
__device__ __forceinline__ float bf2f(unsigned short h) {
  return __uint_as_float(((unsigned)h) << 16);
}

// async global->LDS, 16B per lane; dest = wave-uniform base + lane*16
#define GLD16(ldsp, gp) __builtin_amdgcn_global_load_lds( \
    (const __attribute__((address_space(1))) void*)(gp),  \
    (__attribute__((address_space(3))) void*)(ldsp), 16, 0, 0)

__device__ __forceinline__ void conv8(const float* s, unsigned short* d) {
  float4 a = *(const float4*)s;
  float4 b = *(const float4*)(s + 4);
  int4 pk = make_int4(
      (int)((unsigned)f2bf(a.x) | ((unsigned)f2bf(a.y) << 16)),
      (int)((unsigned)f2bf(a.z) | ((unsigned)f2bf(a.w) << 16)),
      (int)((unsigned)f2bf(b.x) | ((unsigned)f2bf(b.y) << 16)),
      (int)((unsigned)f2bf(b.z) | ((unsigned)f2bf(b.w) << 16)));
  *(int4*)d = pk;
}

// ---------------- fp32 -> bf16 bulk convert ----------------
__global__ __launch_bounds__(256) void conv_k(const float* __restrict__ s,
    unsigned short* __restrict__ d) {
  size_t i = (size_t)(blockIdx.x * 256 + threadIdx.x) * 8;
  conv8(s + i, d + i);
}

// 3 equal regions (eg,eu,ed), contiguous dest
__global__ __launch_bounds__(256) void conv3_k(const float* __restrict__ s0,
    const float* __restrict__ s1, const float* __restrict__ s2,
    unsigned short* __restrict__ d, int per) {   // per = blocks per region
  int b = blockIdx.x;
  const float* s = (b < per) ? s0 : (b < 2 * per) ? s1 : s2;
  int sb = (b < per) ? b : (b < 2 * per) ? b - per : b - 2 * per;
  size_t di = (size_t)b * 2048 + threadIdx.x * 8;
  size_t si = (size_t)sb * 2048 + threadIdx.x * 8;
  conv8(s + si, d + di);
}

// 2 regions (qw 864 blocks, ow 288), contiguous dest
__global__ __launch_bounds__(256) void conv2_k(const float* __restrict__ s0,
    const float* __restrict__ s1, unsigned short* __restrict__ d, int per0) {
  int b = blockIdx.x;
  const float* s = (b < per0) ? s0 : s1;
  int sb = (b < per0) ? b : b - per0;
  size_t di = (size_t)b * 2048 + threadIdx.x * 8;
  size_t si = (size_t)sb * 2048 + threadIdx.x * 8;
  conv8(s + si, d + di);
}

// ---------------- embedding: x = emb[tok]*sqrt(D) ----------------
__global__ __launch_bounds__(256) void embed_k(const int* __restrict__ tok,
    const float* __restrict__ emb, float* __restrict__ x,
    unsigned short* __restrict__ xbf) {
  int idx = blockIdx.x * 256 + threadIdx.x;   // < 2048*768
  int s = idx / DM, d = idx % DM;
  float v = emb[(size_t)tok[s] * DM + d] * 27.712812921102035f;
  x[idx] = v;
  xbf[idx] = f2bf(v);
}

// ================= pipelined 128x256 GEMM engine =================
// BM=128, BN=256, BK=64, 512 thr = 8 waves (2M x 4N), per-wave 64x64.
// Tri-buffered LDS (144 KB), prefetch depth 2, counted vmcnt(6), raw
// s_barrier, setprio. N % 256 == 0, K % 64 == 0, K/64 >= 3.
// Z batching: B at z*b_z, C at z*c_z, M = cnt[z % zmod] (or M), A rows
// optionally gathered via glist[z % zmod].
template<bool GATHER, bool OBF16>
__global__ __launch_bounds__(512) void gemm256_k(
    const unsigned short* __restrict__ A, long long lda,
    const unsigned short* __restrict__ B, long long ldb, long long b_z,
    void* __restrict__ C, long long ldc, long long c_z,
    int M, int Kd, int mT, int nT, int Z, int zmod,
    const int* __restrict__ glist, long long gl_z,
    const int* __restrict__ cnt)
{
  int nwg = gridDim.x, bid = blockIdx.x;
  int q = nwg >> 3, r = nwg & 7;
  int xcd = bid & 7, j = bid >> 3;
  int wid = (xcd < r ? xcd * (q + 1) : r * (q + 1) + (xcd - r) * q) + j;
  int z = wid % Z; int rem = wid / Z;
  int mt = rem % mT, nt = rem / mT;
  int zz = z % zmod;
  int Mz = cnt ? cnt[zz] : M;
  int m0 = mt * 128, n0 = nt * 256;
  if (m0 >= Mz) return;
  (void)nT;

  const unsigned short* Bz = B + (size_t)z * b_z;

  // 3 bufs x 6 halves (A0,A1,B0,B1,B2,B3) x (64 rows x 64 cols) bf16
  __shared__ __align__(16) unsigned short lds[3 * 6 * 4096];

  int t = threadIdx.x, w = t >> 6, lane = t & 63;
  int wm = (w >> 2) * 64, wn = (w & 3) * 64;
  int fr = lane & 15, ksg = lane >> 4;
  int lrow = lane >> 3;                 // 0..7
  int lchunk = ((lane & 7) ^ lrow) * 8; // pre-swizzled source chunk

  // staging source pointers (halves: 0,1 = A; 2..5 = B)
  const unsigned short* sp[6];
  #pragma unroll
  for (int hh = 0; hh < 2; ++hh) {
    int gr = m0 + hh * 64 + w * 8 + lrow; if (gr >= Mz) gr = Mz - 1;
    int arow;
    if constexpr (GATHER) arow = glist[(size_t)zz * gl_z + gr]; else arow = gr;
    sp[hh] = A + (size_t)arow * lda + lchunk;
  }
  #pragma unroll
  for (int hh = 0; hh < 4; ++hh)
    sp[2 + hh] = Bz + (size_t)(n0 + hh * 64 + w * 8 + lrow) * ldb + lchunk;

  int rdA = (w >> 2) * 4096;        // this wave's A half
  int rdB = (2 + (w & 3)) * 4096;   // this wave's B half
  int stDst = w * 512;              // wave dest offset within a half (elems)

  int rx = fr & 7;
  int off0 = (ksg ^ rx) * 8;
  int off1 = ((4 + ksg) ^ rx) * 8;

  int KT = Kd >> 6;
  f32x4 acc[4][4] = {};

  // prologue: stage K-tiles 0 and 1
  #pragma unroll
  for (int h = 0; h < 6; ++h)
    GLD16(&lds[h * 4096 + stDst], sp[h]);
  #pragma unroll
  for (int h = 0; h < 6; ++h)
    GLD16(&lds[(6 + h) * 4096 + stDst], sp[h] + 64);
  asm volatile("s_waitcnt vmcnt(6)" ::: "memory");   // tile 0 landed
  __builtin_amdgcn_s_barrier();
  __builtin_amdgcn_sched_barrier(0);

  int buf = 0;
  for (int kt = 0; kt < KT; ++kt) {
    const unsigned short* Abl = &lds[buf * 6 * 4096 + rdA];
    const unsigned short* Bbl = &lds[buf * 6 * 4096 + rdB];
    int pf = (kt + 2 < KT);
    int pbuf = buf + 2; if (pbuf >= 3) pbuf -= 3;
    unsigned short* pd = &lds[pbuf * 6 * 4096 + stDst];
    long long koff = (long long)(kt + 2) * 64;

    if (pf) {
      GLD16(pd + 0 * 4096, sp[0] + koff);
      GLD16(pd + 1 * 4096, sp[1] + koff);
      GLD16(pd + 2 * 4096, sp[2] + koff);
    }
    {
      bf16x8 af[4], bv[4];
      #pragma unroll
      for (int m = 0; m < 4; ++m)
        af[m] = *(const bf16x8*)&Abl[(m * 16 + fr) * 64 + off0];
      #pragma unroll
      for (int n = 0; n < 4; ++n)
        bv[n] = *(const bf16x8*)&Bbl[(n * 16 + fr) * 64 + off0];
      __builtin_amdgcn_s_setprio(1);
      #pragma unroll
      for (int m = 0; m < 4; ++m)
        #pragma unroll
        for (int n = 0; n < 4; ++n)
          acc[m][n] = __builtin_amdgcn_mfma_f32_16x16x32_bf16(
              af[m], bv[n], acc[m][n], 0, 0, 0);
      __builtin_amdgcn_s_setprio(0);
    }
    if (pf) {
      GLD16(pd + 3 * 4096, sp[3] + koff);
      GLD16(pd + 4 * 4096, sp[4] + koff);
      GLD16(pd + 5 * 4096, sp[5] + koff);
    }
    {
      bf16x8 af[4], bv[4];
      #pragma unroll
      for (int m = 0; m < 4; ++m)
        af[m] = *(const bf16x8*)&Abl[(m * 16 + fr) * 64 + off1];
      #pragma unroll
      for (int n = 0; n < 4; ++n)
        bv[n] = *(const bf16x8*)&Bbl[(n * 16 + fr) * 64 + off1];
      __builtin_amdgcn_s_setprio(1);
      #pragma unroll
      for (int m = 0; m < 4; ++m)
        #pragma unroll
        for (int n = 0; n < 4; ++n)
          acc[m][n] = __builtin_amdgcn_mfma_f32_16x16x32_bf16(
              af[m], bv[n], acc[m][n], 0, 0, 0);
      __builtin_amdgcn_s_setprio(0);
    }
    if (pf) {
      asm volatile("s_waitcnt vmcnt(6)" ::: "memory");
    } else if (kt + 1 < KT) {
      asm volatile("s_waitcnt vmcnt(0)" ::: "memory");
    }
    __builtin_amdgcn_s_barrier();
    __builtin_amdgcn_sched_barrier(0);
    buf = buf + 1; if (buf == 3) buf = 0;
  }

  // epilogue
  int rb = ksg * 4;
  #pragma unroll
  for (int m = 0; m < 4; ++m) {
    #pragma unroll
    for (int n = 0; n < 4; ++n) {
      #pragma unroll
      for (int rr = 0; rr < 4; ++rr) {
        int row = m0 + wm + m * 16 + rb + rr;
        if (row >= Mz) continue;
        size_t off = (size_t)z * c_z + (size_t)row * ldc +
                     (n0 + wn + n * 16 + fr);
        if constexpr (OBF16) ((unsigned short*)C)[off] = f2bf(acc[m][n][rr]);
        else                 ((float*)C)[off] = acc[m][n][rr];
      }
    }
  }
}

// ---------------- bf16 MFMA GEMM, m97 structure ----------------
template<bool GATHER, bool BIAS, bool OBF16>
__global__ __launch_bounds__(256) void gemm_k(
    const unsigned short* __restrict__ A, long long lda, long long a_z,
    const unsigned short* __restrict__ B, long long ldb, long long b_z,
    const float* __restrict__ bias,
    void* __restrict__ C, long long ldc, long long c_z,
    int M, int N, int Kd, float scale,
    const int* __restrict__ glist, long long gl_z,
    const int* __restrict__ cnt, int mT, int nT, int Z)
{
  int nwg = gridDim.x, bid = blockIdx.x;
  int q = nwg >> 3, r = nwg & 7;
  int xcd = bid & 7, j = bid >> 3;
  int wid = (xcd < r ? xcd * (q + 1) : r * (q + 1) + (xcd - r) * q) + j;
  int z = wid % Z; int rem = wid / Z;
  int mt = rem % mT, nt = rem / mT;

  int Mz = cnt ? cnt[z] : M;
  int m0 = mt * 128, n0 = nt * 128;
  if (m0 >= Mz) return;

  const unsigned short* Ab = A + (size_t)z * a_z;
  const unsigned short* Bb = B + (size_t)z * b_z;

  __shared__ __align__(16) unsigned short As[128 * 64];
  __shared__ __align__(16) unsigned short Bs[128 * 64];

  int t = threadIdx.x, w = t >> 6, lane = t & 63;
  int wm = (w >> 1) * 64, wn = (w & 1) * 64;
  int fr = lane & 15, ksg = lane >> 4;
  int lrow = lane >> 3;
  int lchunk = ((lane & 7) ^ lrow) * 8;

  const unsigned short* ap[4];
  const unsigned short* bp[4];
  unsigned short* la[4];
  unsigned short* lb[4];
  #pragma unroll
  for (int i = 0; i < 4; ++i) {
    int rrow = w * 32 + i * 8 + lrow;
    int gr = m0 + rrow; if (gr >= Mz) gr = Mz - 1;
    int arow; if constexpr (GATHER) arow = glist[(size_t)z * gl_z + gr]; else arow = gr;
    ap[i] = Ab + (size_t)arow * lda + lchunk;
    int br = n0 + rrow; if (br >= N) br = N - 1;
    bp[i] = Bb + (size_t)br * ldb + lchunk;
    la[i] = &As[(w * 32 + i * 8) * 64];
    lb[i] = &Bs[(w * 32 + i * 8) * 64];
  }

  int rx = fr & 7;
  int off0 = ((0 + ksg) ^ rx) * 8;
  int off1 = ((4 + ksg) ^ rx) * 8;

  f32x4 acc[4][4] = {};

  for (int k0 = 0; k0 < Kd; k0 += 64) {
    #pragma unroll
    for (int i = 0; i < 4; ++i) GLD16(la[i], ap[i] + k0);
    #pragma unroll
    for (int i = 0; i < 4; ++i) GLD16(lb[i], bp[i] + k0);
    __syncthreads();
    #pragma unroll
    for (int kb = 0; kb < 2; ++kb) {
      int offk = kb ? off1 : off0;
      bf16x8 af[4], bv[4];
      #pragma unroll
      for (int m = 0; m < 4; ++m)
        af[m] = *(const bf16x8*)&As[(wm + m * 16 + fr) * 64 + offk];
      #pragma unroll
      for (int n = 0; n < 4; ++n)
        bv[n] = *(const bf16x8*)&Bs[(wn + n * 16 + fr) * 64 + offk];
      #pragma unroll
      for (int m = 0; m < 4; ++m)
        #pragma unroll
        for (int n = 0; n < 4; ++n)
          acc[m][n] = __builtin_amdgcn_mfma_f32_16x16x32_bf16(
              af[m], bv[n], acc[m][n], 0, 0, 0);
    }
    __syncthreads();
  }

  int rb = ksg * 4;
  #pragma unroll
  for (int m = 0; m < 4; ++m) {
    #pragma unroll
    for (int n = 0; n < 4; ++n) {
      int col = n0 + wn + n * 16 + fr;
      if (col >= N) continue;
      #pragma unroll
      for (int rr = 0; rr < 4; ++rr) {
        int row = m0 + wm + m * 16 + rb + rr;
        if (row >= Mz) continue;
        float v = acc[m][n][rr] * scale;
        if constexpr (BIAS) v += bias[col];
        size_t off = (size_t)z * c_z + (size_t)row * ldc + col;
        if constexpr (OBF16) ((unsigned short*)C)[off] = f2bf(v);
        else                 ((float*)C)[off] = v;
      }
    }
  }
}

// ---------------- V transpose: vt[h][d][k] = qkv[k][2D + h*64 + d] ----------------
__global__ __launch_bounds__(256) void transpose_v_k(
    const unsigned short* __restrict__ qkv, unsigned short* __restrict__ vt) {
  int kt = blockIdx.x;   // 0..31
  int h  = blockIdx.y;   // 0..11
  __shared__ unsigned short tile[64][72];
  int t = threadIdx.x;
  int r = t >> 2;             // 0..63
  int c0 = (t & 3) * 16;      // 0,16,32,48
  const unsigned short* src =
      qkv + (size_t)(kt * 64 + r) * (3 * DM) + 2 * DM + h * DHD + c0;
  *(int4*)&tile[r][c0]     = *(const int4*)(src);
  *(int4*)&tile[r][c0 + 8] = *(const int4*)(src + 8);
  __syncthreads();
  unsigned u[8];
  #pragma unroll
  for (int j = 0; j < 8; ++j)
    u[j] = (unsigned)tile[c0 + 2 * j][r] | ((unsigned)tile[c0 + 2 * j + 1][r] << 16);
  unsigned short* dst = vt + (size_t)(h * DHD + r) * SQ + kt * 64 + c0;
  *(int4*)dst       = make_int4((int)u[0], (int)u[1], (int)u[2], (int)u[3]);
  *(int4*)(dst + 8) = make_int4((int)u[4], (int)u[5], (int)u[6], (int)u[7]);
}

// ---------------- flash attention (2-wave blocks, 32 q-rows) ----------------
// grid = NHD*64 = 768 blocks (3/CU exact), 128 threads = 2 waves,
// wave w owns q-rows [w*16, w*16+16). K-tile 128 keys; online softmax.
__global__ __launch_bounds__(128) void flash_k(
    const unsigned short* __restrict__ qkv,   // [SQ][3*DM] bf16
    const unsigned short* __restrict__ vt,    // [NHD*DHD][SQ] bf16 (V^T)
    unsigned short* __restrict__ o)           // [SQ][DM] bf16
{
  int nwg = gridDim.x, bid = blockIdx.x;      // nwg = 768
  int cpx = nwg >> 3;
  int wid = (bid & 7) * cpx + (bid >> 3);
  int h  = wid >> 6;          // qt fastest -> same-head blocks share XCD L2
  int qt = wid & 63;
  int q0 = qt * 32;

  __shared__ __align__(16) unsigned short Ks[128 * 64];
  __shared__ __align__(16) unsigned short Vs[128 * 64];
  __shared__ __align__(16) unsigned short Ps[2][16 * 136];

  int t = threadIdx.x, w = t >> 6, lane = t & 63;
  int fr = lane & 15, ksg = lane >> 4;
  int lrow = lane >> 3;
  int lchunk = ((lane & 7) ^ lrow) * 8;

  // ---- stage Q (32x64) into Ks, pull A-frags ----
  const unsigned short* qbase = qkv + (size_t)q0 * (3 * DM) + h * DHD;
  #pragma unroll
  for (int i = 0; i < 2; ++i) {
    int rrow = w * 16 + i * 8 + lrow;
    GLD16(&Ks[(w * 16 + i * 8) * 64], qbase + (size_t)rrow * (3 * DM) + lchunk);
  }
  __syncthreads();
  bf16x8 qf[2];
  {
    int row = w * 16 + fr, ph = fr & 7;
    qf[0] = *(const bf16x8*)&Ks[row * 64 + ((ksg ^ ph) * 8)];
    qf[1] = *(const bf16x8*)&Ks[row * 64 + (((4 + ksg) ^ ph) * 8)];
  }
  __syncthreads();

  const unsigned short* kbase = qkv + DM + h * DHD;
  const unsigned short* vb = vt + (size_t)(h * DHD) * SQ;

  f32x4 oacc[4] = {};
  float m_r[4] = {-1e30f, -1e30f, -1e30f, -1e30f};
  float l_r[4] = {0.f, 0.f, 0.f, 0.f};

  for (int kt = 0; kt < SQ / 128; ++kt) {
    int kk0 = kt * 128;
    #pragma unroll
    for (int i = 0; i < 8; ++i) {
      int rrow = w * 64 + i * 8 + lrow;
      GLD16(&Ks[(w * 64 + i * 8) * 64],
            kbase + (size_t)(kk0 + rrow) * (3 * DM) + lchunk);
    }
    #pragma unroll
    for (int i = 0; i < 8; ++i) {
      int p = w * 64 + i * 8 + lrow;
      GLD16(&Vs[(w * 64 + i * 8) * 64],
            vb + (size_t)(p >> 1) * SQ + kk0 + (p & 1) * 64 + lchunk);
    }
    __syncthreads();

    f32x4 sacc[8] = {};
    #pragma unroll
    for (int kb = 0; kb < 2; ++kb) {
      #pragma unroll
      for (int n = 0; n < 8; ++n) {
        int row = n * 16 + fr;
        bf16x8 bvv = *(const bf16x8*)&Ks[row * 64 +
            (((kb * 4 + ksg) ^ (fr & 7)) * 8)];
        sacc[n] = __builtin_amdgcn_mfma_f32_16x16x32_bf16(
            qf[kb], bvv, sacc[n], 0, 0, 0);
      }
    }

    #pragma unroll
    for (int r = 0; r < 4; ++r) {
      float mx = sacc[0][r];
      #pragma unroll
      for (int n = 1; n < 8; ++n) mx = fmaxf(mx, sacc[n][r]);
      mx = fmaxf(mx, __shfl_xor(mx, 1));
      mx = fmaxf(mx, __shfl_xor(mx, 2));
      mx = fmaxf(mx, __shfl_xor(mx, 4));
      mx = fmaxf(mx, __shfl_xor(mx, 8));
      float mn = fmaxf(m_r[r], mx * 0.125f);
      float resc = __expf(m_r[r] - mn);
      m_r[r] = mn;
      #pragma unroll
      for (int n = 0; n < 4; ++n) oacc[n][r] *= resc;
      float rs = 0.f;
      #pragma unroll
      for (int n = 0; n < 8; ++n) {
        float p = __expf(sacc[n][r] * 0.125f - mn);
        rs += p;
        Ps[w][(ksg * 4 + r) * 136 + n * 16 + fr] = f2bf(p);
      }
      rs += __shfl_xor(rs, 1);
      rs += __shfl_xor(rs, 2);
      rs += __shfl_xor(rs, 4);
      rs += __shfl_xor(rs, 8);
      l_r[r] = l_r[r] * resc + rs;
    }

    #pragma unroll
    for (int ksi = 0; ksi < 4; ++ksi) {
      bf16x8 pa = *(const bf16x8*)&Ps[w][fr * 136 + ksi * 32 + ksg * 8];
      #pragma unroll
      for (int n = 0; n < 4; ++n) {
        int p = (n * 16 + fr) * 2 + (ksi >> 1);
        int c = (ksi & 1) * 4 + ksg;
        bf16x8 bvv = *(const bf16x8*)&Vs[p * 64 + ((c ^ (p & 7)) * 8)];
        oacc[n] = __builtin_amdgcn_mfma_f32_16x16x32_bf16(
            pa, bvv, oacc[n], 0, 0, 0);
      }
    }
    __syncthreads();
  }

  unsigned short* ob = o + (size_t)(q0 + w * 16) * DM + h * DHD;
  #pragma unroll
  for (int r = 0; r < 4; ++r) {
    float invl = 1.f / l_r[r];
    int qrow = ksg * 4 + r;
    #pragma unroll
    for (int n = 0; n < 4; ++n)
      ob[(size_t)qrow * DM + n * 16 + fr] = f2bf(oacc[n][r] * invl);
  }
}

// ---------------- x = LN(x + add) ----------------
__global__ __launch_bounds__(256) void add_ln_k(const float* __restrict__ xin,
    const float* __restrict__ add, const float* __restrict__ w,
    const float* __restrict__ b, float* __restrict__ xout,
    unsigned short* __restrict__ xbf) {
  int row = blockIdx.x, t = threadIdx.x;
  const float* xi = xin + (size_t)row * DM;
  const float* ai = add + (size_t)row * DM;
  float v[3]; float s = 0.f, sq = 0.f;
  #pragma unroll
  for (int i = 0; i < 3; ++i) {
    int idx = t + i * 256;
    v[i] = xi[idx] + ai[idx];
    s += v[i]; sq += v[i] * v[i];
  }
  #pragma unroll
  for (int o = 32; o; o >>= 1) { s += __shfl_xor(s, o); sq += __shfl_xor(sq, o); }
  __shared__ float rsm[4], rqm[4];
  int wv = t >> 6;
  if ((t & 63) == 0) { rsm[wv] = s; rqm[wv] = sq; }
  __syncthreads();
  s = rsm[0] + rsm[1] + rsm[2] + rsm[3];
  sq = rqm[0] + rqm[1] + rqm[2] + rqm[3];
  float mean = s * (1.f / 768.f);
  float var = sq * (1.f / 768.f) - mean * mean;
  float inv = rsqrtf(var + 1e-5f);
  float* xo = xout + (size_t)row * DM;
  unsigned short* xb = xbf + (size_t)row * DM;
  #pragma unroll
  for (int i = 0; i < 3; ++i) {
    int idx = t + i * 256;
    float y = (v[i] - mean) * inv * w[idx] + b[idx];
    xo[idx] = y; xb[idx] = f2bf(y);
  }
}

// ---------------- gate: 8 dots, top-2, softmax, expert bucket lists ----------------
__global__ void gate_topk_k(const float* __restrict__ x, const float* __restrict__ gw,
    float* __restrict__ tw, int* __restrict__ ti, int* __restrict__ cnt,
    int* __restrict__ lists, int* __restrict__ slot) {
  int sIdx = blockIdx.x, lane = threadIdx.x;  // 64 threads
  const float* xr = x + (size_t)sIdx * DM;
  float acc[NE] = {};
  for (int d = lane; d < DM; d += 64) {
    float xv = xr[d];
    #pragma unroll
    for (int e = 0; e < NE; ++e) acc[e] += xv * gw[e * DM + d];
  }
  #pragma unroll
  for (int e = 0; e < NE; ++e) {
    #pragma unroll
    for (int o = 32; o; o >>= 1) acc[e] += __shfl_down(acc[e], o);
  }
  if (lane == 0) {
    float v0 = -1e30f, v1 = -1e30f; int i0 = 0, i1 = 0;
    #pragma unroll
    for (int e = 0; e < NE; ++e) {
      float v = acc[e];
      if (v > v0) { v1 = v0; i1 = i0; v0 = v; i0 = e; }
      else if (v > v1) { v1 = v; i1 = e; }
    }
    float e1 = expf(v1 - v0);
    float inv = 1.f / (1.f + e1);
    tw[sIdx * 2] = inv; tw[sIdx * 2 + 1] = e1 * inv;
    ti[sIdx * 2] = i0;  ti[sIdx * 2 + 1] = i1;
    int p0 = atomicAdd(&cnt[i0], 1); lists[i0 * SQ + p0] = sIdx; slot[sIdx * 2] = p0;
    int p1 = atomicAdd(&cnt[i1], 1); lists[i1 * SQ + p1] = sIdx; slot[sIdx * 2 + 1] = p1;
  }
}

__global__ void zero_k(int* __restrict__ c) {
  if (threadIdx.x < NE) c[threadIdx.x] = 0;
}

// ---------------- hh = silu(hg) * hu (in-place into hg) ----------------
__global__ __launch_bounds__(256) void silu_mul_k(unsigned short* __restrict__ hg,
    const unsigned short* __restrict__ hu, const int* __restrict__ cnt) {
  int e = blockIdx.y, sl = blockIdx.x;
  if (sl >= cnt[e]) return;
  size_t base = ((size_t)e * SQ + sl) * FF;
  int t = threadIdx.x;
  #pragma unroll
  for (int i = 0; i < FF / 256; ++i) {
    size_t idx = base + t + i * 256;
    float g = bf2f(hg[idx]);
    float u = bf2f(hu[idx]);
    float sv = g / (1.f + expf(-g));
    hg[idx] = f2bf(sv * u);
  }
}

// ---------------- moe combine + LN ----------------
__global__ __launch_bounds__(256) void combine_ln_k(const float* __restrict__ xin,
    const float* __restrict__ ye, const float* __restrict__ tw,
    const int* __restrict__ ti, const int* __restrict__ slot,
    const float* __restrict__ w, const float* __restrict__ b,
    float* __restrict__ xout, unsigned short* __restrict__ xbf) {
  int row = blockIdx.x, t = threadIdx.x;
  int e0 = ti[row * 2], e1 = ti[row * 2 + 1];
  int p0 = slot[row * 2], p1 = slot[row * 2 + 1];
  float w0 = tw[row * 2], w1 = tw[row * 2 + 1];
  const float* y0 = ye + ((size_t)e0 * SQ + p0) * DM;
  const float* y1 = ye + ((size_t)e1 * SQ + p1) * DM;
  const float* xi = xin + (size_t)row * DM;
  float v[3]; float s = 0.f, sq = 0.f;
  #pragma unroll
  for (int i = 0; i < 3; ++i) {
    int idx = t + i * 256;
    v[i] = xi[idx] + w0 * y0[idx] + w1 * y1[idx];
    s += v[i]; sq += v[i] * v[i];
  }
  #pragma unroll
  for (int o = 32; o; o >>= 1) { s += __shfl_xor(s, o); sq += __shfl_xor(sq, o); }
  __shared__ float rsm[4], rqm[4];
  int wv = t >> 6;
  if ((t & 63) == 0) { rsm[wv] = s; rqm[wv] = sq; }
  __syncthreads();
  s = rsm[0] + rsm[1] + rsm[2] + rsm[3];
  sq = rqm[0] + rqm[1] + rqm[2] + rqm[3];
  float mean = s * (1.f / 768.f);
  float var = sq * (1.f / 768.f) - mean * mean;
  float inv = rsqrtf(var + 1e-5f);
  float* xo = xout + (size_t)row * DM;
  unsigned short* xb = xbf + (size_t)row * DM;
  #pragma unroll
  for (int i = 0; i < 3; ++i) {
    int idx = t + i * 256;
    float y = (v[i] - mean) * inv * w[idx] + b[idx];
    xo[idx] = y; xb[idx] = f2bf(y);
  }
}

// ---------------- final RMSNorm -> bf16 ----------------
__global__ __launch_bounds__(256) void rms_k(const float* __restrict__ x,
    const float* __restrict__ rw, unsigned short* __restrict__ xbf) {
  int row = blockIdx.x, t = threadIdx.x;
  const float* xi = x + (size_t)row * DM;
  float v[3]; float sq = 0.f;
  #pragma unroll
  for (int i = 0; i < 3; ++i) {
    int idx = t + i * 256;
    v[i] = xi[idx];
    sq += v[i] * v[i];
  }
  #pragma unroll
  for (int o = 32; o; o >>= 1) sq += __shfl_xor(sq, o);
  __shared__ float rqm[4];
  int wv = t >> 6;
  if ((t & 63) == 0) rqm[wv] = sq;
  __syncthreads();
  sq = rqm[0] + rqm[1] + rqm[2] + rqm[3];
  float inv = rsqrtf(sq * (1.f / 768.f) + 1.1920929e-07f);
  unsigned short* xb = xbf + (size_t)row * DM;
  #pragma unroll
  for (int i = 0; i < 3; ++i) {
    int idx = t + i * 256;
    xb[idx] = f2bf(v[i] * inv * rw[idx]);
  }
}

// ================= host =================
extern "C" void kernel_launch(void* const* d_in, const int* in_sizes, int n_in,
                              void* d_out, int out_size, void* d_ws, size_t ws_size,
                              hipStream_t stream) {
  (void)in_sizes; (void)n_in; (void)out_size; (void)ws_size;
  const int*   tokens = (const int*)d_in[0];
  const float* emb    = (const float*)d_in[1];
  const float* qkv_w  = (const float*)d_in[2];
  const float* qkv_b  = (const float*)d_in[3];
  const float* out_w  = (const float*)d_in[4];
  const float* out_b  = (const float*)d_in[5];
  const float* ln1_w  = (const float*)d_in[6];
  const float* ln1_b  = (const float*)d_in[7];
  const float* ln2_w  = (const float*)d_in[8];
  const float* ln2_b  = (const float*)d_in[9];
  const float* gate_w = (const float*)d_in[10];
  const float* eg_w   = (const float*)d_in[11];
  const float* eu_w   = (const float*)d_in[12];
  const float* ed_w   = (const float*)d_in[13];
  const float* rms_w  = (const float*)d_in[14];
  float* out = (float*)d_out;

  char* wsb = (char*)d_ws;
  float*          x_f    = (float*)(wsb + 0);                   // 6291456
  unsigned short* x_bf   = (unsigned short*)(wsb + 6291456);    // 3145728
  unsigned short* qkv_bf = (unsigned short*)(wsb + 9437184);    // 9437184
  unsigned short* vt     = (unsigned short*)(wsb + 18874368);   // 3145728
  unsigned short* o_bf   = (unsigned short*)(wsb + 22020096);   // 3145728
  float*          tmp_f  = (float*)(wsb + 25165824);            // 6291456
  float*          tw     = (float*)(wsb + 31457280);            // 16384
  int*            ti     = (int*)(wsb + 31473664);              // 16384
  int*            cnt    = (int*)(wsb + 31490048);              // 256
  int*            lists  = (int*)(wsb + 31490304);              // 65536
  int*            slot   = (int*)(wsb + 31555840);              // 16384
  unsigned short* emb_bf = (unsigned short*)(wsb + 31572224);   // 49152000
  unsigned short* wbf    = (unsigned short*)(wsb + 80724224);   // 61341696
  unsigned short* hg     = (unsigned short*)(wsb + 142065920);
  unsigned short* hu     = (unsigned short*)(wsb + 142065920 + 50331648);
  float*          ye     = (float*)(wsb + 142065920 + 50331648); // overlaps hu (dead)

  unsigned short* qw_bf = wbf;                 // 1769472
  unsigned short* ow_bf = wbf + 1769472;       // 589824
  unsigned short* eg_bf = wbf + 2359296;       // 9437184
  unsigned short* eu_bf = wbf + 11796480;      // 9437184  (= eg_bf + 8*FF*DM)
  unsigned short* ed_bf = wbf + 21233664;      // 9437184  (= eu_bf + 8*FF*DM)

  conv_k<<<12000, 256, 0, stream>>>(emb, emb_bf);
  embed_k<<<SQ * DM / 256, 256, 0, stream>>>(tokens, emb, x_f, x_bf);

  for (int l = 0; l < NL; ++l) {
    const float* qw = qkv_w + (size_t)l * 3 * DM * DM;
    const float* qb = qkv_b + (size_t)l * 3 * DM;
    const float* ob = out_b + (size_t)l * DM;
    const float* ow = out_w + (size_t)l * DM * DM;
    const float* gw = gate_w + (size_t)l * NE * DM;
    const float* egw = eg_w + (size_t)l * NE * FF * DM;
    const float* euw = eu_w + (size_t)l * NE * FF * DM;
    const float* edw = ed_w + (size_t)l * NE * DM * FF;

    conv2_k<<<1152, 256, 0, stream>>>(qw, ow, qw_bf, 864);
    conv3_k<<<13824, 256, 0, stream>>>(egw, euw, edw, eg_bf, 4608);

    // qkv = x @ qkv_w^T + b  -> bf16
    gemm_k<false, true, true><<<16 * 18, 256, 0, stream>>>(
        x_bf, DM, 0, qw_bf, DM, 0, qb, qkv_bf, 3 * DM, 0,
        SQ, 3 * DM, DM, 1.f, nullptr, 0, nullptr, 16, 18, 1);

    transpose_v_k<<<dim3(SQ / 64, NHD), 256, 0, stream>>>(qkv_bf, vt);

    // fused flash attention -> o_bf  (768 blocks, 2 waves, 32 q-rows)
    flash_k<<<NHD * 64, 128, 0, stream>>>(qkv_bf, vt, o_bf);

    // attn out-proj -> tmp_f (fp32)
    gemm_k<false, true, false><<<16 * 6, 256, 0, stream>>>(
        o_bf, DM, 0, ow_bf, DM, 0, ob, tmp_f, DM, 0,
        SQ, DM, DM, 1.f, nullptr, 0, nullptr, 16, 6, 1);

    add_ln_k<<<SQ, 256, 0, stream>>>(x_f, tmp_f, ln1_w + l * DM, ln1_b + l * DM,
                                     x_f, x_bf);

    zero_k<<<1, 64, 0, stream>>>(cnt);
    gate_topk_k<<<SQ, 64, 0, stream>>>(x_f, gw, tw, ti, cnt, lists, slot);

    // eg + eu in ONE pipelined dispatch: Z=16 (z<8 -> gate, z>=8 -> up);
    // eu_bf = eg_bf + 8*b_z, hu = hg + 8*c_z (contiguous) -> plain z indexing.
    gemm256_k<true, true><<<16 * 6 * 16, 512, 0, stream>>>(
        x_bf, DM, eg_bf, DM, (long long)FF * DM,
        hg, FF, (long long)SQ * FF,
        SQ, DM, 16, 6, 16, 8, lists, SQ, cnt);

    silu_mul_k<<<dim3(SQ, NE), 256, 0, stream>>>(hg, hu, cnt);

    // ye = hh @ ed^T (fp32 out)
    gemm_k<false, false, false><<<16 * 6 * NE, 256, 0, stream>>>(
        hg, FF, (long long)SQ * FF, ed_bf, FF, (long long)DM * FF, nullptr,
        ye, DM, (long long)SQ * DM,
        SQ, DM, FF, 1.f, nullptr, 0, cnt, 16, 6, NE);

    combine_ln_k<<<SQ, 256, 0, stream>>>(x_f, ye, tw, ti, slot,
                                         ln2_w + l * DM, ln2_b + l * DM,
                                         x_f, x_bf);
  }

  rms_k<<<SQ, 256, 0, stream>>>(x_f, rms_w, x_bf);

  // logits = xn @ emb_bf^T (fp32 out) -- pipelined engine
  gemm256_k<false, false><<<16 * 125, 512, 0, stream>>>(
      x_bf, DM, emb_bf, DM, 0, out, NV, 0,
      SQ, DM, 16, 125, 1, 1, nullptr, 0, nullptr);
}

// Round 7
// 801.029 us; speedup vs baseline: 1.4214x; 1.0151x over previous
//
#include <hip/hip_runtime.h>

// ---- problem dims ----
#define SQ   2048
#define DM   768
#define NHD  12
#define DHD  64
#define FF   1536
#define NE   8
#define NL   2
#define NV   32000

typedef __attribute__((ext_vector_type(8))) short bf16x8;
typedef __attribute__((ext_vector_type(4))) float f32x4;

__device__ __forceinline__ unsigned short f2bf(float f) {
  unsigned u = __float_as_uint(f);
  return (unsigned short)((u + 0x7fffu + ((u >> 16) & 1u)) >> 16);
}
__device__ __forceinline__ float bf2f(unsigned short h) {
  return __uint_as_float(((unsigned)h) << 16);
}

// async global->LDS, 16B per lane; dest = wave-uniform base + lane*16
#define GLD16(ldsp, gp) __builtin_amdgcn_global_load_lds( \
    (const __attribute__((address_space(1))) void*)(gp),  \
    (__attribute__((address_space(3))) void*)(ldsp), 16, 0, 0)

__device__ __forceinline__ void conv8(const float* s, unsigned short* d) {
  float4 a = *(const float4*)s;
  float4 b = *(const float4*)(s + 4);
  int4 pk = make_int4(
      (int)((unsigned)f2bf(a.x) | ((unsigned)f2bf(a.y) << 16)),
      (int)((unsigned)f2bf(a.z) | ((unsigned)f2bf(a.w) << 16)),
      (int)((unsigned)f2bf(b.x) | ((unsigned)f2bf(b.y) << 16)),
      (int)((unsigned)f2bf(b.z) | ((unsigned)f2bf(b.w) << 16)));
  *(int4*)d = pk;
}

// ---------------- fp32 -> bf16 bulk convert ----------------
__global__ __launch_bounds__(256) void conv_k(const float* __restrict__ s,
    unsigned short* __restrict__ d) {
  size_t i = (size_t)(blockIdx.x * 256 + threadIdx.x) * 8;
  conv8(s + i, d + i);
}

// 3 equal regions (eg,eu,ed), contiguous dest
__global__ __launch_bounds__(256) void conv3_k(const float* __restrict__ s0,
    const float* __restrict__ s1, const float* __restrict__ s2,
    unsigned short* __restrict__ d, int per) {
  int b = blockIdx.x;
  const float* s = (b < per) ? s0 : (b < 2 * per) ? s1 : s2;
  int sb = (b < per) ? b : (b < 2 * per) ? b - per : b - 2 * per;
  size_t di = (size_t)b * 2048 + threadIdx.x * 8;
  size_t si = (size_t)sb * 2048 + threadIdx.x * 8;
  conv8(s + si, d + di);
}

// 2 regions (qw 864 blocks, ow 288), contiguous dest
__global__ __launch_bounds__(256) void conv2_k(const float* __restrict__ s0,
    const float* __restrict__ s1, unsigned short* __restrict__ d, int per0) {
  int b = blockIdx.x;
  const float* s = (b < per0) ? s0 : s1;
  int sb = (b < per0) ? b : b - per0;
  size_t di = (size_t)b * 2048 + threadIdx.x * 8;
  size_t si = (size_t)sb * 2048 + threadIdx.x * 8;
  conv8(s + si, d + di);
}

// ---------------- embedding: x = emb[tok]*sqrt(D) ----------------
__global__ __launch_bounds__(256) void embed_k(const int* __restrict__ tok,
    const float* __restrict__ emb, float* __restrict__ x,
    unsigned short* __restrict__ xbf) {
  int idx = blockIdx.x * 256 + threadIdx.x;   // < 2048*768
  int s = idx / DM, d = idx % DM;
  float v = emb[(size_t)tok[s] * DM + d] * 27.712812921102035f;
  x[idx] = v;
  xbf[idx] = f2bf(v);
}

// ================= 256x256 8-phase GEMM (logits engine) =================
// BM=BN=256, BK=64, 512 thr = 8 waves (2M x 4N), wave tile 128x64.
// LDS 128 KB dbuf. Per K-tile: 4 double-barrier phases, stages (8 GLD) in
// phases 0-1, vmcnt(0) only at tile boundary. Exact tiles: M%256==0,
// N%256==0, K%64==0, K/64>=2. fp32 C.
__global__ __launch_bounds__(512, 2) void gemm8p_k(
    const unsigned short* __restrict__ A, long long lda,
    const unsigned short* __restrict__ B, long long ldb,
    float* __restrict__ C, long long ldc,
    int Kd, int mT)
{
  int nwg = gridDim.x, bid = blockIdx.x;
  int q = nwg >> 3, r = nwg & 7;
  int xcd = bid & 7, j = bid >> 3;
  int wid = (xcd < r ? xcd * (q + 1) : r * (q + 1) + (xcd - r) * q) + j;
  int mt = wid % mT, nt = wid / mT;     // m-fastest: B-panel reuse in XCD L2
  int m0 = mt * 256, n0 = nt * 256;

  // [buf][A=0/B=1][256 rows * 64 cols]
  __shared__ __align__(16) unsigned short lds[2][2][16384];

  int t = threadIdx.x, w = t >> 6, lane = t & 63;
  int wm = w >> 2, wn = w & 3;          // wave tile: rows wm*128, cols wn*64
  int fr = lane & 15, ksg = lane >> 4;

  // staging: round i covers rows i*64..i*64+63; thread t -> row t>>3,
  // source chunk XOR-swizzled so LDS[row][c] = global[row][c ^ (row&7)]
  int srow = t >> 3;
  int schunk = ((t & 7) ^ (srow & 7)) * 8;
  const unsigned short* sa[4];
  const unsigned short* sb[4];
  #pragma unroll
  for (int i = 0; i < 4; ++i) {
    sa[i] = A + (size_t)(m0 + i * 64 + srow) * lda + schunk;
    sb[i] = B + (size_t)(n0 + i * 64 + srow) * ldb + schunk;
  }

  int KT = Kd >> 6;
  f32x4 acc[8][4] = {};

#define STAGE_A(bufi, k0) { \
    _Pragma("unroll") \
    for (int i = 0; i < 4; ++i) \
      GLD16(&lds[bufi][0][(i * 64 + w * 8) * 64], sa[i] + (k0)); }
#define STAGE_B(bufi, k0) { \
    _Pragma("unroll") \
    for (int i = 0; i < 4; ++i) \
      GLD16(&lds[bufi][1][(i * 64 + w * 8) * 64], sb[i] + (k0)); }
#define MFMA16(MQ) { \
    _Pragma("unroll") \
    for (int m = 0; m < 4; ++m) \
      _Pragma("unroll") \
      for (int n = 0; n < 4; ++n) \
        acc[(MQ) * 4 + m][n] = __builtin_amdgcn_mfma_f32_16x16x32_bf16( \
            afr[m], bfr[n], acc[(MQ) * 4 + m][n], 0, 0, 0); }

  // prologue: stage tile 0
  STAGE_A(0, 0); STAGE_B(0, 0);
  asm volatile("s_waitcnt vmcnt(0)" ::: "memory");
  __builtin_amdgcn_s_barrier();
  __builtin_amdgcn_sched_barrier(0);

  int buf = 0;
  for (int kt = 0; kt < KT; ++kt) {
    const unsigned short* Al = &lds[buf][0][0];
    const unsigned short* Bl = &lds[buf][1][0];
    int pf = (kt + 1 < KT);
    long long koff = (long long)(kt + 1) * 64;
    bf16x8 bfr[4], afr[4];

    // ---- phase 0: read B(kb0) + A(mq0,kb0); stage A(t+1); MFMA mq0 ----
    {
      int ko = ((0 + ksg) ^ (fr & 7)) * 8;
      #pragma unroll
      for (int n = 0; n < 4; ++n)
        bfr[n] = *(const bf16x8*)&Bl[(wn * 64 + n * 16 + fr) * 64 + ko];
      #pragma unroll
      for (int m = 0; m < 4; ++m)
        afr[m] = *(const bf16x8*)&Al[(wm * 128 + m * 16 + fr) * 64 + ko];
      if (pf) STAGE_A(buf ^ 1, koff);
      __builtin_amdgcn_s_barrier();
      asm volatile("s_waitcnt lgkmcnt(0)" ::: "memory");
      __builtin_amdgcn_sched_barrier(0);
      __builtin_amdgcn_s_setprio(1);
      MFMA16(0);
      __builtin_amdgcn_s_setprio(0);
      __builtin_amdgcn_s_barrier();
    }
    // ---- phase 1: read A(mq1,kb0); stage B(t+1); MFMA mq1 (reuse bfr) ----
    {
      int ko = ((0 + ksg) ^ (fr & 7)) * 8;
      #pragma unroll
      for (int m = 0; m < 4; ++m)
        afr[m] = *(const bf16x8*)&Al[(wm * 128 + 64 + m * 16 + fr) * 64 + ko];
      if (pf) STAGE_B(buf ^ 1, koff);
      __builtin_amdgcn_s_barrier();
      asm volatile("s_waitcnt lgkmcnt(0)" ::: "memory");
      __builtin_amdgcn_sched_barrier(0);
      __builtin_amdgcn_s_setprio(1);
      MFMA16(1);
      __builtin_amdgcn_s_setprio(0);
      __builtin_amdgcn_s_barrier();
    }
    // ---- phase 2: read B(kb1) + A(mq0,kb1); MFMA mq0 ----
    {
      int ko = ((4 + ksg) ^ (fr & 7)) * 8;
      #pragma unroll
      for (int n = 0; n < 4; ++n)
        bfr[n] = *(const bf16x8*)&Bl[(wn * 64 + n * 16 + fr) * 64 + ko];
      #pragma unroll
      for (int m = 0; m < 4; ++m)
        afr[m] = *(const bf16x8*)&Al[(wm * 128 + m * 16 + fr) * 64 + ko];
      __builtin_amdgcn_s_barrier();
      asm volatile("s_waitcnt lgkmcnt(0)" ::: "memory");
      __builtin_amdgcn_sched_barrier(0);
      __builtin_amdgcn_s_setprio(1);
      MFMA16(0);
      __builtin_amdgcn_s_setprio(0);
      __builtin_amdgcn_s_barrier();
    }
    // ---- phase 3: read A(mq1,kb1); MFMA mq1; tile boundary ----
    {
      int ko = ((4 + ksg) ^ (fr & 7)) * 8;
      #pragma unroll
      for (int m = 0; m < 4; ++m)
        afr[m] = *(const bf16x8*)&Al[(wm * 128 + 64 + m * 16 + fr) * 64 + ko];
      __builtin_amdgcn_s_barrier();
      asm volatile("s_waitcnt lgkmcnt(0)" ::: "memory");
      __builtin_amdgcn_sched_barrier(0);
      __builtin_amdgcn_s_setprio(1);
      MFMA16(1);
      __builtin_amdgcn_s_setprio(0);
      if (pf) asm volatile("s_waitcnt vmcnt(0)" ::: "memory");
      __builtin_amdgcn_s_barrier();
      __builtin_amdgcn_sched_barrier(0);
    }
    buf ^= 1;
  }
#undef STAGE_A
#undef STAGE_B
#undef MFMA16

  // epilogue
  int rb = ksg * 4;
  #pragma unroll
  for (int M = 0; M < 8; ++M)
    #pragma unroll
    for (int n = 0; n < 4; ++n)
      #pragma unroll
      for (int rr = 0; rr < 4; ++rr)
        C[(size_t)(m0 + wm * 128 + M * 16 + rb + rr) * ldc +
          (n0 + wn * 64 + n * 16 + fr)] = acc[M][n][rr];
}

// ================= pipelined 128x256 GEMM engine (Z/gather) =================
template<bool GATHER, bool OBF16>
__global__ __launch_bounds__(512) void gemm256_k(
    const unsigned short* __restrict__ A, long long lda,
    const unsigned short* __restrict__ B, long long ldb, long long b_z,
    void* __restrict__ C, long long ldc, long long c_z,
    int M, int Kd, int mT, int nT, int Z, int zmod,
    const int* __restrict__ glist, long long gl_z,
    const int* __restrict__ cnt)
{
  int nwg = gridDim.x, bid = blockIdx.x;
  int q = nwg >> 3, r = nwg & 7;
  int xcd = bid & 7, j = bid >> 3;
  int wid = (xcd < r ? xcd * (q + 1) : r * (q + 1) + (xcd - r) * q) + j;
  int z = wid % Z; int rem = wid / Z;
  int mt = rem % mT, nt = rem / mT;
  int zz = z % zmod;
  int Mz = cnt ? cnt[zz] : M;
  int m0 = mt * 128, n0 = nt * 256;
  if (m0 >= Mz) return;
  (void)nT;

  const unsigned short* Bz = B + (size_t)z * b_z;

  __shared__ __align__(16) unsigned short lds[3 * 6 * 4096];

  int t = threadIdx.x, w = t >> 6, lane = t & 63;
  int wm = (w >> 2) * 64, wn = (w & 3) * 64;
  int fr = lane & 15, ksg = lane >> 4;
  int lrow = lane >> 3;
  int lchunk = ((lane & 7) ^ lrow) * 8;

  const unsigned short* sp[6];
  #pragma unroll
  for (int hh = 0; hh < 2; ++hh) {
    int gr = m0 + hh * 64 + w * 8 + lrow; if (gr >= Mz) gr = Mz - 1;
    int arow;
    if constexpr (GATHER) arow = glist[(size_t)zz * gl_z + gr]; else arow = gr;
    sp[hh] = A + (size_t)arow * lda + lchunk;
  }
  #pragma unroll
  for (int hh = 0; hh < 4; ++hh)
    sp[2 + hh] = Bz + (size_t)(n0 + hh * 64 + w * 8 + lrow) * ldb + lchunk;

  int rdA = (w >> 2) * 4096;
  int rdB = (2 + (w & 3)) * 4096;
  int stDst = w * 512;

  int rx = fr & 7;
  int off0 = (ksg ^ rx) * 8;
  int off1 = ((4 + ksg) ^ rx) * 8;

  int KT = Kd >> 6;
  f32x4 acc[4][4] = {};

  #pragma unroll
  for (int h = 0; h < 6; ++h)
    GLD16(&lds[h * 4096 + stDst], sp[h]);
  #pragma unroll
  for (int h = 0; h < 6; ++h)
    GLD16(&lds[(6 + h) * 4096 + stDst], sp[h] + 64);
  asm volatile("s_waitcnt vmcnt(6)" ::: "memory");
  __builtin_amdgcn_s_barrier();
  __builtin_amdgcn_sched_barrier(0);

  int buf = 0;
  for (int kt = 0; kt < KT; ++kt) {
    const unsigned short* Abl = &lds[buf * 6 * 4096 + rdA];
    const unsigned short* Bbl = &lds[buf * 6 * 4096 + rdB];
    int pf = (kt + 2 < KT);
    int pbuf = buf + 2; if (pbuf >= 3) pbuf -= 3;
    unsigned short* pd = &lds[pbuf * 6 * 4096 + stDst];
    long long koff = (long long)(kt + 2) * 64;

    if (pf) {
      GLD16(pd + 0 * 4096, sp[0] + koff);
      GLD16(pd + 1 * 4096, sp[1] + koff);
      GLD16(pd + 2 * 4096, sp[2] + koff);
    }
    {
      bf16x8 af[4], bv[4];
      #pragma unroll
      for (int m = 0; m < 4; ++m)
        af[m] = *(const bf16x8*)&Abl[(m * 16 + fr) * 64 + off0];
      #pragma unroll
      for (int n = 0; n < 4; ++n)
        bv[n] = *(const bf16x8*)&Bbl[(n * 16 + fr) * 64 + off0];
      __builtin_amdgcn_s_setprio(1);
      #pragma unroll
      for (int m = 0; m < 4; ++m)
        #pragma unroll
        for (int n = 0; n < 4; ++n)
          acc[m][n] = __builtin_amdgcn_mfma_f32_16x16x32_bf16(
              af[m], bv[n], acc[m][n], 0, 0, 0);
      __builtin_amdgcn_s_setprio(0);
    }
    if (pf) {
      GLD16(pd + 3 * 4096, sp[3] + koff);
      GLD16(pd + 4 * 4096, sp[4] + koff);
      GLD16(pd + 5 * 4096, sp[5] + koff);
    }
    {
      bf16x8 af[4], bv[4];
      #pragma unroll
      for (int m = 0; m < 4; ++m)
        af[m] = *(const bf16x8*)&Abl[(m * 16 + fr) * 64 + off1];
      #pragma unroll
      for (int n = 0; n < 4; ++n)
        bv[n] = *(const bf16x8*)&Bbl[(n * 16 + fr) * 64 + off1];
      __builtin_amdgcn_s_setprio(1);
      #pragma unroll
      for (int m = 0; m < 4; ++m)
        #pragma unroll
        for (int n = 0; n < 4; ++n)
          acc[m][n] = __builtin_amdgcn_mfma_f32_16x16x32_bf16(
              af[m], bv[n], acc[m][n], 0, 0, 0);
      __builtin_amdgcn_s_setprio(0);
    }
    if (pf) {
      asm volatile("s_waitcnt vmcnt(6)" ::: "memory");
    } else if (kt + 1 < KT) {
      asm volatile("s_waitcnt vmcnt(0)" ::: "memory");
    }
    __builtin_amdgcn_s_barrier();
    __builtin_amdgcn_sched_barrier(0);
    buf = buf + 1; if (buf == 3) buf = 0;
  }

  int rb = ksg * 4;
  #pragma unroll
  for (int m = 0; m < 4; ++m) {
    #pragma unroll
    for (int n = 0; n < 4; ++n) {
      #pragma unroll
      for (int rr = 0; rr < 4; ++rr) {
        int row = m0 + wm + m * 16 + rb + rr;
        if (row >= Mz) continue;
        size_t off = (size_t)z * c_z + (size_t)row * ldc +
                     (n0 + wn + n * 16 + fr);
        if constexpr (OBF16) ((unsigned short*)C)[off] = f2bf(acc[m][n][rr]);
        else                 ((float*)C)[off] = acc[m][n][rr];
      }
    }
  }
}

// ---------------- bf16 MFMA GEMM, m97 structure ----------------
template<bool GATHER, bool BIAS, bool OBF16>
__global__ __launch_bounds__(256) void gemm_k(
    const unsigned short* __restrict__ A, long long lda, long long a_z,
    const unsigned short* __restrict__ B, long long ldb, long long b_z,
    const float* __restrict__ bias,
    void* __restrict__ C, long long ldc, long long c_z,
    int M, int N, int Kd, float scale,
    const int* __restrict__ glist, long long gl_z,
    const int* __restrict__ cnt, int mT, int nT, int Z)
{
  int nwg = gridDim.x, bid = blockIdx.x;
  int q = nwg >> 3, r = nwg & 7;
  int xcd = bid & 7, j = bid >> 3;
  int wid = (xcd < r ? xcd * (q + 1) : r * (q + 1) + (xcd - r) * q) + j;
  int z = wid % Z; int rem = wid / Z;
  int mt = rem % mT, nt = rem / mT;

  int Mz = cnt ? cnt[z] : M;
  int m0 = mt * 128, n0 = nt * 128;
  if (m0 >= Mz) return;

  const unsigned short* Ab = A + (size_t)z * a_z;
  const unsigned short* Bb = B + (size_t)z * b_z;

  __shared__ __align__(16) unsigned short As[128 * 64];
  __shared__ __align__(16) unsigned short Bs[128 * 64];

  int t = threadIdx.x, w = t >> 6, lane = t & 63;
  int wm = (w >> 1) * 64, wn = (w & 1) * 64;
  int fr = lane & 15, ksg = lane >> 4;
  int lrow = lane >> 3;
  int lchunk = ((lane & 7) ^ lrow) * 8;

  const unsigned short* ap[4];
  const unsigned short* bp[4];
  unsigned short* la[4];
  unsigned short* lb[4];
  #pragma unroll
  for (int i = 0; i < 4; ++i) {
    int rrow = w * 32 + i * 8 + lrow;
    int gr = m0 + rrow; if (gr >= Mz) gr = Mz - 1;
    int arow; if constexpr (GATHER) arow = glist[(size_t)z * gl_z + gr]; else arow = gr;
    ap[i] = Ab + (size_t)arow * lda + lchunk;
    int br = n0 + rrow; if (br >= N) br = N - 1;
    bp[i] = Bb + (size_t)br * ldb + lchunk;
    la[i] = &As[(w * 32 + i * 8) * 64];
    lb[i] = &Bs[(w * 32 + i * 8) * 64];
  }

  int rx = fr & 7;
  int off0 = ((0 + ksg) ^ rx) * 8;
  int off1 = ((4 + ksg) ^ rx) * 8;

  f32x4 acc[4][4] = {};

  for (int k0 = 0; k0 < Kd; k0 += 64) {
    #pragma unroll
    for (int i = 0; i < 4; ++i) GLD16(la[i], ap[i] + k0);
    #pragma unroll
    for (int i = 0; i < 4; ++i) GLD16(lb[i], bp[i] + k0);
    __syncthreads();
    #pragma unroll
    for (int kb = 0; kb < 2; ++kb) {
      int offk = kb ? off1 : off0;
      bf16x8 af[4], bv[4];
      #pragma unroll
      for (int m = 0; m < 4; ++m)
        af[m] = *(const bf16x8*)&As[(wm + m * 16 + fr) * 64 + offk];
      #pragma unroll
      for (int n = 0; n < 4; ++n)
        bv[n] = *(const bf16x8*)&Bs[(wn + n * 16 + fr) * 64 + offk];
      #pragma unroll
      for (int m = 0; m < 4; ++m)
        #pragma unroll
        for (int n = 0; n < 4; ++n)
          acc[m][n] = __builtin_amdgcn_mfma_f32_16x16x32_bf16(
              af[m], bv[n], acc[m][n], 0, 0, 0);
    }
    __syncthreads();
  }

  int rb = ksg * 4;
  #pragma unroll
  for (int m = 0; m < 4; ++m) {
    #pragma unroll
    for (int n = 0; n < 4; ++n) {
      int col = n0 + wn + n * 16 + fr;
      if (col >= N) continue;
      #pragma unroll
      for (int rr = 0; rr < 4; ++rr) {
        int row = m0 + wm + m * 16 + rb + rr;
        if (row >= Mz) continue;
        float v = acc[m][n][rr] * scale;
        if constexpr (BIAS) v += bias[col];
        size_t off = (size_t)z * c_z + (size_t)row * ldc + col;
        if constexpr (OBF16) ((unsigned short*)C)[off] = f2bf(v);
        else                 ((float*)C)[off] = v;
      }
    }
  }
}

// ---------------- V transpose: vt[h][d][k] = qkv[k][2D + h*64 + d] ----------------
__global__ __launch_bounds__(256) void transpose_v_k(
    const unsigned short* __restrict__ qkv, unsigned short* __restrict__ vt) {
  int kt = blockIdx.x;   // 0..31
  int h  = blockIdx.y;   // 0..11
  __shared__ unsigned short tile[64][72];
  int t = threadIdx.x;
  int r = t >> 2;             // 0..63
  int c0 = (t & 3) * 16;      // 0,16,32,48
  const unsigned short* src =
      qkv + (size_t)(kt * 64 + r) * (3 * DM) + 2 * DM + h * DHD + c0;
  *(int4*)&tile[r][c0]     = *(const int4*)(src);
  *(int4*)&tile[r][c0 + 8] = *(const int4*)(src + 8);
  __syncthreads();
  unsigned u[8];
  #pragma unroll
  for (int j = 0; j < 8; ++j)
    u[j] = (unsigned)tile[c0 + 2 * j][r] | ((unsigned)tile[c0 + 2 * j + 1][r] << 16);
  unsigned short* dst = vt + (size_t)(h * DHD + r) * SQ + kt * 64 + c0;
  *(int4*)dst       = make_int4((int)u[0], (int)u[1], (int)u[2], (int)u[3]);
  *(int4*)(dst + 8) = make_int4((int)u[4], (int)u[5], (int)u[6], (int)u[7]);
}

// ---------------- flash attention (2-wave blocks, 32 q-rows) ----------------
__global__ __launch_bounds__(128) void flash_k(
    const unsigned short* __restrict__ qkv,   // [SQ][3*DM] bf16
    const unsigned short* __restrict__ vt,    // [NHD*DHD][SQ] bf16 (V^T)
    unsigned short* __restrict__ o)           // [SQ][DM] bf16
{
  int nwg = gridDim.x, bid = blockIdx.x;      // nwg = 768
  int cpx = nwg >> 3;
  int wid = (bid & 7) * cpx + (bid >> 3);
  int h  = wid >> 6;
  int qt = wid & 63;
  int q0 = qt * 32;

  __shared__ __align__(16) unsigned short Ks[128 * 64];
  __shared__ __align__(16) unsigned short Vs[128 * 64];
  __shared__ __align__(16) unsigned short Ps[2][16 * 136];

  int t = threadIdx.x, w = t >> 6, lane = t & 63;
  int fr = lane & 15, ksg = lane >> 4;
  int lrow = lane >> 3;
  int lchunk = ((lane & 7) ^ lrow) * 8;

  const unsigned short* qbase = qkv + (size_t)q0 * (3 * DM) + h * DHD;
  #pragma unroll
  for (int i = 0; i < 2; ++i) {
    int rrow = w * 16 + i * 8 + lrow;
    GLD16(&Ks[(w * 16 + i * 8) * 64], qbase + (size_t)rrow * (3 * DM) + lchunk);
  }
  __syncthreads();
  bf16x8 qf[2];
  {
    int row = w * 16 + fr, ph = fr & 7;
    qf[0] = *(const bf16x8*)&Ks[row * 64 + ((ksg ^ ph) * 8)];
    qf[1] = *(const bf16x8*)&Ks[row * 64 + (((4 + ksg) ^ ph) * 8)];
  }
  __syncthreads();

  const unsigned short* kbase = qkv + DM + h * DHD;
  const unsigned short* vb = vt + (size_t)(h * DHD) * SQ;

  f32x4 oacc[4] = {};
  float m_r[4] = {-1e30f, -1e30f, -1e30f, -1e30f};
  float l_r[4] = {0.f, 0.f, 0.f, 0.f};

  for (int kt = 0; kt < SQ / 128; ++kt) {
    int kk0 = kt * 128;
    #pragma unroll
    for (int i = 0; i < 8; ++i) {
      int rrow = w * 64 + i * 8 + lrow;
      GLD16(&Ks[(w * 64 + i * 8) * 64],
            kbase + (size_t)(kk0 + rrow) * (3 * DM) + lchunk);
    }
    #pragma unroll
    for (int i = 0; i < 8; ++i) {
      int p = w * 64 + i * 8 + lrow;
      GLD16(&Vs[(w * 64 + i * 8) * 64],
            vb + (size_t)(p >> 1) * SQ + kk0 + (p & 1) * 64 + lchunk);
    }
    __syncthreads();

    f32x4 sacc[8] = {};
    #pragma unroll
    for (int kb = 0; kb < 2; ++kb) {
      #pragma unroll
      for (int n = 0; n < 8; ++n) {
        int row = n * 16 + fr;
        bf16x8 bvv = *(const bf16x8*)&Ks[row * 64 +
            (((kb * 4 + ksg) ^ (fr & 7)) * 8)];
        sacc[n] = __builtin_amdgcn_mfma_f32_16x16x32_bf16(
            qf[kb], bvv, sacc[n], 0, 0, 0);
      }
    }

    #pragma unroll
    for (int r = 0; r < 4; ++r) {
      float mx = sacc[0][r];
      #pragma unroll
      for (int n = 1; n < 8; ++n) mx = fmaxf(mx, sacc[n][r]);
      mx = fmaxf(mx, __shfl_xor(mx, 1));
      mx = fmaxf(mx, __shfl_xor(mx, 2));
      mx = fmaxf(mx, __shfl_xor(mx, 4));
      mx = fmaxf(mx, __shfl_xor(mx, 8));
      float mn = fmaxf(m_r[r], mx * 0.125f);
      float resc = __expf(m_r[r] - mn);
      m_r[r] = mn;
      #pragma unroll
      for (int n = 0; n < 4; ++n) oacc[n][r] *= resc;
      float rs = 0.f;
      #pragma unroll
      for (int n = 0; n < 8; ++n) {
        float p = __expf(sacc[n][r] * 0.125f - mn);
        rs += p;
        Ps[w][(ksg * 4 + r) * 136 + n * 16 + fr] = f2bf(p);
      }
      rs += __shfl_xor(rs, 1);
      rs += __shfl_xor(rs, 2);
      rs += __shfl_xor(rs, 4);
      rs += __shfl_xor(rs, 8);
      l_r[r] = l_r[r] * resc + rs;
    }

    #pragma unroll
    for (int ksi = 0; ksi < 4; ++ksi) {
      bf16x8 pa = *(const bf16x8*)&Ps[w][fr * 136 + ksi * 32 + ksg * 8];
      #pragma unroll
      for (int n = 0; n < 4; ++n) {
        int p = (n * 16 + fr) * 2 + (ksi >> 1);
        int c = (ksi & 1) * 4 + ksg;
        bf16x8 bvv = *(const bf16x8*)&Vs[p * 64 + ((c ^ (p & 7)) * 8)];
        oacc[n] = __builtin_amdgcn_mfma_f32_16x16x32_bf16(
            pa, bvv, oacc[n], 0, 0, 0);
      }
    }
    __syncthreads();
  }

  unsigned short* ob = o + (size_t)(q0 + w * 16) * DM + h * DHD;
  #pragma unroll
  for (int r = 0; r < 4; ++r) {
    float invl = 1.f / l_r[r];
    int qrow = ksg * 4 + r;
    #pragma unroll
    for (int n = 0; n < 4; ++n)
      ob[(size_t)qrow * DM + n * 16 + fr] = f2bf(oacc[n][r] * invl);
  }
}

// ---------------- x = LN(x + add) ----------------
__global__ __launch_bounds__(256) void add_ln_k(const float* __restrict__ xin,
    const float* __restrict__ add, const float* __restrict__ w,
    const float* __restrict__ b, float* __restrict__ xout,
    unsigned short* __restrict__ xbf) {
  int row = blockIdx.x, t = threadIdx.x;
  const float* xi = xin + (size_t)row * DM;
  const float* ai = add + (size_t)row * DM;
  float v[3]; float s = 0.f, sq = 0.f;
  #pragma unroll
  for (int i = 0; i < 3; ++i) {
    int idx = t + i * 256;
    v[i] = xi[idx] + ai[idx];
    s += v[i]; sq += v[i] * v[i];
  }
  #pragma unroll
  for (int o = 32; o; o >>= 1) { s += __shfl_xor(s, o); sq += __shfl_xor(sq, o); }
  __shared__ float rsm[4], rqm[4];
  int wv = t >> 6;
  if ((t & 63) == 0) { rsm[wv] = s; rqm[wv] = sq; }
  __syncthreads();
  s = rsm[0] + rsm[1] + rsm[2] + rsm[3];
  sq = rqm[0] + rqm[1] + rqm[2] + rqm[3];
  float mean = s * (1.f / 768.f);
  float var = sq * (1.f / 768.f) - mean * mean;
  float inv = rsqrtf(var + 1e-5f);
  float* xo = xout + (size_t)row * DM;
  unsigned short* xb = xbf + (size_t)row * DM;
  #pragma unroll
  for (int i = 0; i < 3; ++i) {
    int idx = t + i * 256;
    float y = (v[i] - mean) * inv * w[idx] + b[idx];
    xo[idx] = y; xb[idx] = f2bf(y);
  }
}

// ---------------- gate: 8 dots, top-2, softmax, expert bucket lists ----------------
__global__ void gate_topk_k(const float* __restrict__ x, const float* __restrict__ gw,
    float* __restrict__ tw, int* __restrict__ ti, int* __restrict__ cnt,
    int* __restrict__ lists, int* __restrict__ slot) {
  int sIdx = blockIdx.x, lane = threadIdx.x;  // 64 threads
  const float* xr = x + (size_t)sIdx * DM;
  float acc[NE] = {};
  for (int d = lane; d < DM; d += 64) {
    float xv = xr[d];
    #pragma unroll
    for (int e = 0; e < NE; ++e) acc[e] += xv * gw[e * DM + d];
  }
  #pragma unroll
  for (int e = 0; e < NE; ++e) {
    #pragma unroll
    for (int o = 32; o; o >>= 1) acc[e] += __shfl_down(acc[e], o);
  }
  if (lane == 0) {
    float v0 = -1e30f, v1 = -1e30f; int i0 = 0, i1 = 0;
    #pragma unroll
    for (int e = 0; e < NE; ++e) {
      float v = acc[e];
      if (v > v0) { v1 = v0; i1 = i0; v0 = v; i0 = e; }
      else if (v > v1) { v1 = v; i1 = e; }
    }
    float e1 = expf(v1 - v0);
    float inv = 1.f / (1.f + e1);
    tw[sIdx * 2] = inv; tw[sIdx * 2 + 1] = e1 * inv;
    ti[sIdx * 2] = i0;  ti[sIdx * 2 + 1] = i1;
    int p0 = atomicAdd(&cnt[i0], 1); lists[i0 * SQ + p0] = sIdx; slot[sIdx * 2] = p0;
    int p1 = atomicAdd(&cnt[i1], 1); lists[i1 * SQ + p1] = sIdx; slot[sIdx * 2 + 1] = p1;
  }
}

__global__ void zero_k(int* __restrict__ c) {
  if (threadIdx.x < NE) c[threadIdx.x] = 0;
}

// ---------------- hh = silu(hg) * hu (in-place into hg) ----------------
__global__ __launch_bounds__(256) void silu_mul_k(unsigned short* __restrict__ hg,
    const unsigned short* __restrict__ hu, const int* __restrict__ cnt) {
  int e = blockIdx.y, sl = blockIdx.x;
  if (sl >= cnt[e]) return;
  size_t base = ((size_t)e * SQ + sl) * FF;
  int t = threadIdx.x;
  #pragma unroll
  for (int i = 0; i < FF / 256; ++i) {
    size_t idx = base + t + i * 256;
    float g = bf2f(hg[idx]);
    float u = bf2f(hu[idx]);
    float sv = g / (1.f + expf(-g));
    hg[idx] = f2bf(sv * u);
  }
}

// ---------------- moe combine + LN ----------------
__global__ __launch_bounds__(256) void combine_ln_k(const float* __restrict__ xin,
    const float* __restrict__ ye, const float* __restrict__ tw,
    const int* __restrict__ ti, const int* __restrict__ slot,
    const float* __restrict__ w, const float* __restrict__ b,
    float* __restrict__ xout, unsigned short* __restrict__ xbf) {
  int row = blockIdx.x, t = threadIdx.x;
  int e0 = ti[row * 2], e1 = ti[row * 2 + 1];
  int p0 = slot[row * 2], p1 = slot[row * 2 + 1];
  float w0 = tw[row * 2], w1 = tw[row * 2 + 1];
  const float* y0 = ye + ((size_t)e0 * SQ + p0) * DM;
  const float* y1 = ye + ((size_t)e1 * SQ + p1) * DM;
  const float* xi = xin + (size_t)row * DM;
  float v[3]; float s = 0.f, sq = 0.f;
  #pragma unroll
  for (int i = 0; i < 3; ++i) {
    int idx = t + i * 256;
    v[i] = xi[idx] + w0 * y0[idx] + w1 * y1[idx];
    s += v[i]; sq += v[i] * v[i];
  }
  #pragma unroll
  for (int o = 32; o; o >>= 1) { s += __shfl_xor(s, o); sq += __shfl_xor(sq, o); }
  __shared__ float rsm[4], rqm[4];
  int wv = t >> 6;
  if ((t & 63) == 0) { rsm[wv] = s; rqm[wv] = sq; }
  __syncthreads();
  s = rsm[0] + rsm[1] + rsm[2] + rsm[3];
  sq = rqm[0] + rqm[1] + rqm[2] + rqm[3];
  float mean = s * (1.f / 768.f);
  float var = sq * (1.f / 768.f) - mean * mean;
  float inv = rsqrtf(var + 1e-5f);
  float* xo = xout + (size_t)row * DM;
  unsigned short* xb = xbf + (size_t)row * DM;
  #pragma unroll
  for (int i = 0; i < 3; ++i) {
    int idx = t + i * 256;
    float y = (v[i] - mean) * inv * w[idx] + b[idx];
    xo[idx] = y; xb[idx] = f2bf(y);
  }
}

// ---------------- final RMSNorm -> bf16 ----------------
__global__ __launch_bounds__(256) void rms_k(const float* __restrict__ x,
    const float* __restrict__ rw, unsigned short* __restrict__ xbf) {
  int row = blockIdx.x, t = threadIdx.x;
  const float* xi = x + (size_t)row * DM;
  float v[3]; float sq = 0.f;
  #pragma unroll
  for (int i = 0; i < 3; ++i) {
    int idx = t + i * 256;
    v[i] = xi[idx];
    sq += v[i] * v[i];
  }
  #pragma unroll
  for (int o = 32; o; o >>= 1) sq += __shfl_xor(sq, o);
  __shared__ float rqm[4];
  int wv = t >> 6;
  if ((t & 63) == 0) rqm[wv] = sq;
  __syncthreads();
  sq = rqm[0] + rqm[1] + rqm[2] + rqm[3];
  float inv = rsqrtf(sq * (1.f / 768.f) + 1.1920929e-07f);
  unsigned short* xb = xbf + (size_t)row * DM;
  #pragma unroll
  for (int i = 0; i < 3; ++i) {
    int idx = t + i * 256;
    xb[idx] = f2bf(v[i] * inv * rw[idx]);
  }
}

// ================= host =================
extern "C" void kernel_launch(void* const* d_in, const int* in_sizes, int n_in,
                              void* d_out, int out_size, void* d_ws, size_t ws_size,
                              hipStream_t stream) {
  (void)in_sizes; (void)n_in; (void)out_size; (void)ws_size;
  const int*   tokens = (const int*)d_in[0];
  const float* emb    = (const float*)d_in[1];
  const float* qkv_w  = (const float*)d_in[2];
  const float* qkv_b  = (const float*)d_in[3];
  const float* out_w  = (const float*)d_in[4];
  const float* out_b  = (const float*)d_in[5];
  const float* ln1_w  = (const float*)d_in[6];
  const float* ln1_b  = (const float*)d_in[7];
  const float* ln2_w  = (const float*)d_in[8];
  const float* ln2_b  = (const float*)d_in[9];
  const float* gate_w = (const float*)d_in[10];
  const float* eg_w   = (const float*)d_in[11];
  const float* eu_w   = (const float*)d_in[12];
  const float* ed_w   = (const float*)d_in[13];
  const float* rms_w  = (const float*)d_in[14];
  float* out = (float*)d_out;

  char* wsb = (char*)d_ws;
  float*          x_f    = (float*)(wsb + 0);                   // 6291456
  unsigned short* x_bf   = (unsigned short*)(wsb + 6291456);    // 3145728
  unsigned short* qkv_bf = (unsigned short*)(wsb + 9437184);    // 9437184
  unsigned short* vt     = (unsigned short*)(wsb + 18874368);   // 3145728
  unsigned short* o_bf   = (unsigned short*)(wsb + 22020096);   // 3145728
  float*          tmp_f  = (float*)(wsb + 25165824);            // 6291456
  float*          tw     = (float*)(wsb + 31457280);            // 16384
  int*            ti     = (int*)(wsb + 31473664);              // 16384
  int*            cnt    = (int*)(wsb + 31490048);              // 256
  int*            lists  = (int*)(wsb + 31490304);              // 65536
  int*            slot   = (int*)(wsb + 31555840);              // 16384
  unsigned short* emb_bf = (unsigned short*)(wsb + 31572224);   // 49152000
  unsigned short* wbf    = (unsigned short*)(wsb + 80724224);   // 61341696
  unsigned short* hg     = (unsigned short*)(wsb + 142065920);
  unsigned short* hu     = (unsigned short*)(wsb + 142065920 + 50331648);
  float*          ye     = (float*)(wsb + 142065920 + 50331648); // overlaps hu (dead)

  unsigned short* qw_bf = wbf;                 // 1769472
  unsigned short* ow_bf = wbf + 1769472;       // 589824
  unsigned short* eg_bf = wbf + 2359296;       // 9437184
  unsigned short* ed_bf = wbf + 21233664;      // 9437184

  conv_k<<<12000, 256, 0, stream>>>(emb, emb_bf);
  embed_k<<<SQ * DM / 256, 256, 0, stream>>>(tokens, emb, x_f, x_bf);

  for (int l = 0; l < NL; ++l) {
    const float* qw = qkv_w + (size_t)l * 3 * DM * DM;
    const float* qb = qkv_b + (size_t)l * 3 * DM;
    const float* ob = out_b + (size_t)l * DM;
    const float* ow = out_w + (size_t)l * DM * DM;
    const float* gw = gate_w + (size_t)l * NE * DM;
    const float* egw = eg_w + (size_t)l * NE * FF * DM;
    const float* euw = eu_w + (size_t)l * NE * FF * DM;
    const float* edw = ed_w + (size_t)l * NE * DM * FF;

    conv2_k<<<1152, 256, 0, stream>>>(qw, ow, qw_bf, 864);
    conv3_k<<<13824, 256, 0, stream>>>(egw, euw, edw, eg_bf, 4608);

    // qkv = x @ qkv_w^T + b  -> bf16
    gemm_k<false, true, true><<<16 * 18, 256, 0, stream>>>(
        x_bf, DM, 0, qw_bf, DM, 0, qb, qkv_bf, 3 * DM, 0,
        SQ, 3 * DM, DM, 1.f, nullptr, 0, nullptr, 16, 18, 1);

    transpose_v_k<<<dim3(SQ / 64, NHD), 256, 0, stream>>>(qkv_bf, vt);

    // fused flash attention -> o_bf
    flash_k<<<NHD * 64, 128, 0, stream>>>(qkv_bf, vt, o_bf);

    // attn out-proj -> tmp_f (fp32)
    gemm_k<false, true, false><<<16 * 6, 256, 0, stream>>>(
        o_bf, DM, 0, ow_bf, DM, 0, ob, tmp_f, DM, 0,
        SQ, DM, DM, 1.f, nullptr, 0, nullptr, 16, 6, 1);

    add_ln_k<<<SQ, 256, 0, stream>>>(x_f, tmp_f, ln1_w + l * DM, ln1_b + l * DM,
                                     x_f, x_bf);

    zero_k<<<1, 64, 0, stream>>>(cnt);
    gate_topk_k<<<SQ, 64, 0, stream>>>(x_f, gw, tw, ti, cnt, lists, slot);

    // eg + eu in ONE pipelined dispatch: Z=16 (z<8 gate, z>=8 up)
    gemm256_k<true, true><<<16 * 6 * 16, 512, 0, stream>>>(
        x_bf, DM, eg_bf, DM, (long long)FF * DM,
        hg, FF, (long long)SQ * FF,
        SQ, DM, 16, 6, 16, 8, lists, SQ, cnt);

    silu_mul_k<<<dim3(SQ, NE), 256, 0, stream>>>(hg, hu, cnt);

    // ye = hh @ ed^T (fp32 out)
    gemm_k<false, false, false><<<16 * 6 * NE, 256, 0, stream>>>(
        hg, FF, (long long)SQ * FF, ed_bf, FF, (long long)DM * FF, nullptr,
        ye, DM, (long long)SQ * DM,
        SQ, DM, FF, 1.f, nullptr, 0, cnt, 16, 6, NE);

    combine_ln_k<<<SQ, 256, 0, stream>>>(x_f, ye, tw, ti, slot,
                                         ln2_w + l * DM, ln2_b + l * DM,
                                         x_f, x_bf);
  }

  rms_k<<<SQ, 256, 0, stream>>>(x_f, rms_w, x_bf);

  // logits = xn @ emb_bf^T (fp32 out) -- 256x256 8-phase engine
  // M=2048 (mT=8 x 256), N=32000 (125 x 256), K=768 (12 K-tiles)
  gemm8p_k<<<8 * 125, 512, 0, stream>>>(
      x_bf, DM, emb_bf, DM, out, NV, DM, 8);
}